// Round 11
// baseline (123.731 us; speedup 1.0000x reference)
//
#include <hip/hip_runtime.h>
#include <stdint.h>

typedef unsigned short u16;
typedef __attribute__((ext_vector_type(8))) short short8;
typedef __attribute__((ext_vector_type(4))) short short4v;
typedef __attribute__((ext_vector_type(4))) float f32x4;
typedef __attribute__((ext_vector_type(4))) unsigned short ushort4v;
typedef __attribute__((ext_vector_type(2))) unsigned int uint2v;

#define NB 2
#define NS 2048
#define ND 1024
#define NH 16
#define HDIM 64
#define NHALF 32
#define QSCALE 0.18033688f   /* 0.125 * log2(e) : folds 1/sqrt(64) and exp->exp2 */
#define NEGBIG -3.0e38f      /* finite "-inf": exp2 -> 0, no NaN from arithmetic */

__device__ __forceinline__ float bf2f(u16 u) {
  union { unsigned u; float f; } v; v.u = ((unsigned)u) << 16; return v.f;
}
__device__ __forceinline__ u16 f2bf(float f) {
  union { float f; unsigned u; } v; v.f = f;
  unsigned r = v.u + 0x7fffu + ((v.u >> 16) & 1u);
  return (u16)(r >> 16);
}

// packs lo->bits[15:0], hi->bits[31:16], RNE — same rounding as f2bf
__device__ __forceinline__ unsigned cvt_pk_bf16(float lo, float hi) {
  unsigned r;
  asm("v_cvt_pk_bf16_f32 %0, %1, %2" : "=v"(r) : "v"(lo), "v"(hi));
  return r;
}

__device__ __forceinline__ void gld_lds16(const u16* g, u16* l) {
  void* gv = (void*)g;
  __builtin_amdgcn_global_load_lds((__attribute__((address_space(1))) void*)gv,
                                   (__attribute__((address_space(3))) void*)l, 16, 0, 0);
}

// ---------------- convert x (fp32 -> bf16) ----------------
__global__ void cvt_x(const float* __restrict__ x, u16* __restrict__ xb) {
  int i = blockIdx.x * 256 + threadIdx.x;
  float4 v = ((const float4*)x)[i];
  ushort4v o;
  o.x = f2bf(v.x); o.y = f2bf(v.y); o.z = f2bf(v.z); o.w = f2bf(v.w);
  ((ushort4v*)xb)[i] = o;
}

// ---------------- transpose + convert all 4 weights (z = 0..3) ----------------
__global__ void transpose_w4(const float* __restrict__ W0, const float* __restrict__ W1,
                             const float* __restrict__ W2, const float* __restrict__ W3,
                             u16* __restrict__ dqkv, u16* __restrict__ dout) {
  __shared__ float tile[32][33];
  const int z = blockIdx.z;
  const float* W = (z == 0) ? W0 : (z == 1) ? W1 : (z == 2) ? W2 : W3;
  u16* dst = (z < 3) ? (dqkv + (size_t)z * ND * ND) : dout;
  const int n0 = blockIdx.x * 32, k0 = blockIdx.y * 32;
  const int tx = threadIdx.x, ty = threadIdx.y;
#pragma unroll
  for (int i = 0; i < 4; ++i)
    tile[ty + i * 8][tx] = W[(size_t)(k0 + ty + i * 8) * ND + n0 + tx];
  __syncthreads();
#pragma unroll
  for (int i = 0; i < 4; ++i)
    dst[(size_t)(n0 + ty + i * 8) * ND + k0 + tx] = f2bf(tile[tx][ty + i * 8]);
}

// ---------------- transpose V: [bh][s][d] -> VT [bh][d][s] ----------------
__global__ void transpose_v(const u16* __restrict__ Vb, u16* __restrict__ VT) {
  __shared__ u16 tile[64][72];
  const int bh = blockIdx.y, s0 = blockIdx.x << 6;
  const int tid = threadIdx.x;
  const u16* src = Vb + ((size_t)bh * NS + s0) * HDIM;
  u16* dst = VT + (size_t)bh * HDIM * NS + s0;
#pragma unroll
  for (int it = 0; it < 2; ++it) {
    int i = it * 256 + tid;
    int s = i >> 3, d0 = (i & 7) << 3;
    *(short8*)&tile[s][d0] = *(const short8*)(src + (size_t)s * HDIM + d0);
  }
  __syncthreads();
#pragma unroll
  for (int it = 0; it < 2; ++it) {
    int i = it * 256 + tid;
    int d = i >> 3, ss0 = (i & 7) << 3;
    short8 v;
#pragma unroll
    for (int e = 0; e < 8; ++e) v[e] = tile[ss0 + e][d];
    *(short8*)(dst + (size_t)d * NS + ss0) = v;
  }
}

// ---------------- unified GEMM, BK=64, XOR-swizzled LDS (proven R10) ----------------
template<int MI, int MODE>
__global__ __launch_bounds__(256) void gemm64(
    const u16* __restrict__ A, const u16* __restrict__ BT,
    u16* __restrict__ qo, u16* __restrict__ ko, u16* __restrict__ vo,
    float* __restrict__ fo) {
  __shared__ u16 smem[MI * 2048 + 8192];   // A[(MI*32)][64] | B[128][64]
  const int tid = threadIdx.x;
  const int w = tid >> 6, lane = tid & 63;
  const int lr = lane & 15, lg = lane >> 4;
  const int bm = blockIdx.y * (MI * 32), bn = blockIdx.x << 7;
  const int wr = (w >> 1) * (MI * 16), wc = (w & 1) << 6;
  f32x4 acc[MI][4] = {};

  const int arow = tid >> 3;
  const int aslot = (tid & 7) ^ (arow & 7);
  const u16* ags = A + (size_t)(bm + arow) * ND + (aslot << 3);
  const u16* bgs = BT + (size_t)(bn + arow) * ND + (aslot << 3);
  u16* const As = smem;
  u16* const Bs = smem + MI * 2048;

  int af_off[MI][2], bf_off[4][2];
#pragma unroll
  for (int mi = 0; mi < MI; ++mi)
#pragma unroll
    for (int kk = 0; kk < 2; ++kk)
      af_off[mi][kk] = (wr + mi * 16 + lr) * 64 + ((((kk << 2) + lg) ^ (lr & 7)) << 3);
#pragma unroll
  for (int ni = 0; ni < 4; ++ni)
#pragma unroll
    for (int kk = 0; kk < 2; ++kk)
      bf_off[ni][kk] = (wc + ni * 16 + lr) * 64 + ((((kk << 2) + lg) ^ (lr & 7)) << 3);

  for (int kt = 0; kt < ND; kt += 64) {
#pragma unroll
    for (int it = 0; it < MI; ++it)
      gld_lds16(ags + it * (32 * ND) + kt, As + it * 2048 + w * 512);
#pragma unroll
    for (int it = 0; it < 4; ++it)
      gld_lds16(bgs + it * (32 * ND) + kt, Bs + it * 2048 + w * 512);
    __syncthreads();
#pragma unroll
    for (int kk = 0; kk < 2; ++kk) {
      short8 af[MI], bfr[4];
#pragma unroll
      for (int mi = 0; mi < MI; ++mi)
        af[mi] = *(const short8*)(As + af_off[mi][kk]);
#pragma unroll
      for (int ni = 0; ni < 4; ++ni)
        bfr[ni] = *(const short8*)(Bs + bf_off[ni][kk]);
#pragma unroll
      for (int mi = 0; mi < MI; ++mi)
#pragma unroll
        for (int ni = 0; ni < 4; ++ni)
          acc[mi][ni] = __builtin_amdgcn_mfma_f32_16x16x32_bf16(af[mi], bfr[ni], acc[mi][ni], 0, 0, 0);
    }
    __syncthreads();
  }

  if (MODE == 0) {
#pragma unroll
    for (int mi = 0; mi < MI; ++mi) {
#pragma unroll
      for (int ni = 0; ni < 4; ++ni) {
        const int n = bn + wc + ni * 16 + lr;
        const int which = n >> 10, hh = (n >> 6) & 15, d = n & 63;
        u16* dst = which == 0 ? qo : which == 1 ? ko : vo;
#pragma unroll
        for (int j = 0; j < 4; ++j) {
          const int m = bm + wr + mi * 16 + (lg << 2) + j;
          const int b = m >> 11, s = m & 2047;
          dst[(((size_t)(b * NH + hh) * NS + s) << 6) + d] = f2bf(acc[mi][ni][j]);
        }
      }
    }
  } else {
#pragma unroll
    for (int mi = 0; mi < MI; ++mi)
#pragma unroll
      for (int ni = 0; ni < 4; ++ni)
#pragma unroll
        for (int j = 0; j < 4; ++j) {
          const int m = bm + wr + mi * 16 + (lg << 2) + j;
          const int n = bn + wc + ni * 16 + lr;
          fo[(size_t)m * ND + n] = acc[mi][ni][j];
        }
  }
}

// ---------------- RoPE on Q,K in place (vectorized); Q pre-scaled ----------------
__global__ void rope_k(u16* __restrict__ Qb, u16* __restrict__ Kb,
                       const float* __restrict__ cosT, const float* __restrict__ sinT) {
  int t = blockIdx.x * 256 + threadIdx.x;   // B*H*S*8 threads, 8 bf16 each
  int g = t & 7;
  int s = (t >> 3) & 2047;
  int bh = t >> 14;
  float4 c4 = *(const float4*)(cosT + s * NHALF + (g << 2));
  float4 s4 = *(const float4*)(sinT + s * NHALF + (g << 2));
  size_t off = (((size_t)bh * NS + s) << 6) + (g << 3);
  short8 q = *(const short8*)(Qb + off);
  short8 k = *(const short8*)(Kb + off);
  float cc[4] = {c4.x, c4.y, c4.z, c4.w}, ss[4] = {s4.x, s4.y, s4.z, s4.w};
  short8 qo, ko;
#pragma unroll
  for (int p = 0; p < 4; ++p) {
    float q0 = bf2f((u16)q[2 * p]), q1 = bf2f((u16)q[2 * p + 1]);
    qo[2 * p]     = (short)f2bf((q0 * cc[p] - q1 * ss[p]) * QSCALE);
    qo[2 * p + 1] = (short)f2bf((q0 * ss[p] + q1 * cc[p]) * QSCALE);
    float k0 = bf2f((u16)k[2 * p]), k1 = bf2f((u16)k[2 * p + 1]);
    ko[2 * p]     = (short)f2bf(k0 * cc[p] - k1 * ss[p]);
    ko[2 * p + 1] = (short)f2bf(k0 * ss[p] + k1 * cc[p]);
  }
  *(short8*)(Qb + off) = qo;
  *(short8*)(Kb + off) = ko;
}

// ---------------- flash attention (causal), paired q-tiles, 32q/wave ----------------
// grid 512 blocks of 128 thr (2 waves); block does q-tiles (31-pair) then
// (pair): 33 kv-steps uniform. Wave owns 32 q rows as 2 fragments — each
// K/V fragment read from LDS feeds TWO MFMAs (per-output LDS traffic x0.6).
__global__ __launch_bounds__(128) void attn_k(
    const u16* __restrict__ Qb, const u16* __restrict__ Kb,
    const u16* __restrict__ VT, u16* __restrict__ Ob) {
  __shared__ u16 K2[2][4096];   // [kv=64][d=64], rows 128B, XOR-swizzled
  __shared__ u16 V2[2][4096];   // [d=64][kv=64], rows 128B, XOR-swizzled
  __shared__ u16 Pl[2][2048];   // per wave [q=32][kv=64], rows 128B, XOR-swizzled
  const int tid = threadIdx.x, w = tid >> 6, lane = tid & 63;
  const int lr = lane & 15, lg = lane >> 4;
  const int bid = blockIdx.x;
  const int xcd = bid & 7, i = bid >> 3;          // i in 0..63
  const int bh = xcd * 4 + (i & 3);
  const int pair = i >> 2;                        // 0..15
  const int b = bh >> 4, h = bh & 15;
  const u16* Qp = Qb + (size_t)bh * NS * HDIM;
  const u16* Kp = Kb + (size_t)bh * NS * HDIM;
  const u16* Vp = VT + (size_t)bh * NS * HDIM;    // [d][s]

  // hoisted swizzled LDS offsets (u16 units)
  int kf_off[4][2], vb_off[4][2], pw_off[2][4], pa_off[2][2];
#pragma unroll
  for (int u = 0; u < 4; ++u) {
    const int kvr = (u << 4) + lr;
#pragma unroll
    for (int c = 0; c < 2; ++c)
      kf_off[u][c] = kvr * 64 + ((((c << 6) + (lg << 4)) ^ ((kvr & 7) << 4)) >> 1);
  }
#pragma unroll
  for (int dn = 0; dn < 4; ++dn) {
    const int d = (dn << 4) + lr;
#pragma unroll
    for (int ks = 0; ks < 2; ++ks)
      vb_off[dn][ks] = d * 64 + ((((ks << 6) + (lg << 4)) ^ ((d & 7) << 4)) >> 1);
  }
#pragma unroll
  for (int f = 0; f < 2; ++f) {
#pragma unroll
    for (int u = 0; u < 4; ++u)
      pw_off[f][u] = (f * 16 + lr) * 64 + ((((u << 5) + (lg << 3)) ^ ((lr & 7) << 4)) >> 1);
#pragma unroll
    for (int ks = 0; ks < 2; ++ks)
      pa_off[f][ks] = (f * 16 + lr) * 64 + ((((ks << 6) + (lg << 4)) ^ ((lr & 7) << 4)) >> 1);
  }
  u16* Pw = &Pl[w][0];

  // staging bases: 128 thr cover 16KB per step in 4 chunks x (K,V).
  // wave-instr = 1KB = 8 rows x 128B; row = c*16 + w*8 + (lane>>3).
  const int rr8 = lane >> 3, slot = lane & 7;
  const int soff = ((slot ^ rr8) << 3);          // row&7 == rr8 for all chunks
  const int krow = w * 8 + rr8;
  const u16* kbase = Kp + (size_t)krow * HDIM + soff;
  const u16* vbase = Vp + (size_t)krow * NS + soff;

#define STAGE(BUFI, KV0)                                                           \
  {                                                                                \
    _Pragma("unroll")                                                              \
    for (int c = 0; c < 4; ++c) {                                                  \
      gld_lds16(kbase + (size_t)((KV0) + c * 16) * HDIM, &K2[BUFI][c * 1024 + w * 512]); \
      gld_lds16(vbase + (size_t)(c * 16) * NS + (KV0),   &V2[BUFI][c * 1024 + w * 512]); \
    }                                                                              \
  }

#define STEP(BUF, KVT)                                                            \
  {                                                                               \
    const int kv0 = (KVT) << 6;                                                   \
    if ((KVT) + 1 < nst) STAGE(BUF ^ 1, kv0 + 64);                                \
    const u16* Kl = K2[BUF];                                                      \
    const u16* Vl = V2[BUF];                                                      \
    f32x4 st0[4] = {}, st1[4] = {};                                               \
    __builtin_amdgcn_s_setprio(1);                                                \
    _Pragma("unroll") for (int u = 0; u < 4; ++u)                                 \
      _Pragma("unroll") for (int c = 0; c < 2; ++c) {                             \
        const short8 kf = *(const short8*)(Kl + kf_off[u][c]);                    \
        st0[u] = __builtin_amdgcn_mfma_f32_16x16x32_bf16(kf, qf[0][c], st0[u], 0, 0, 0); \
        st1[u] = __builtin_amdgcn_mfma_f32_16x16x32_bf16(kf, qf[1][c], st1[u], 0, 0, 0); \
      }                                                                           \
    __builtin_amdgcn_s_setprio(0);                                                \
    if (kv0 + 63 > qw) {                                                          \
      _Pragma("unroll") for (int u = 0; u < 4; ++u)                               \
        _Pragma("unroll") for (int j = 0; j < 4; ++j) {                           \
          const int kvg = kv0 + (u << 4) + (lg << 2) + j;                         \
          if (kvg > qw + lr) st0[u][j] = NEGBIG;                                  \
        }                                                                         \
    }                                                                             \
    if (kv0 + 63 > qw + 16) {                                                     \
      _Pragma("unroll") for (int u = 0; u < 4; ++u)                               \
        _Pragma("unroll") for (int j = 0; j < 4; ++j) {                           \
          const int kvg = kv0 + (u << 4) + (lg << 2) + j;                         \
          if (kvg > qw + 16 + lr) st1[u][j] = NEGBIG;                             \
        }                                                                         \
    }                                                                             \
    _Pragma("unroll") for (int u = 0; u < 4; ++u) {                               \
      const float a0 = __builtin_amdgcn_exp2f(st0[u][0]);                         \
      const float a1 = __builtin_amdgcn_exp2f(st0[u][1]);                         \
      const float a2 = __builtin_amdgcn_exp2f(st0[u][2]);                         \
      const float a3 = __builtin_amdgcn_exp2f(st0[u][3]);                         \
      lacc0 += (a0 + a1) + (a2 + a3);                                             \
      uint2v pk0;                                                                 \
      pk0.x = cvt_pk_bf16(a0, a1);                                                \
      pk0.y = cvt_pk_bf16(a2, a3);                                                \
      *(uint2v*)(Pw + pw_off[0][u]) = pk0;                                        \
      const float b0 = __builtin_amdgcn_exp2f(st1[u][0]);                         \
      const float b1 = __builtin_amdgcn_exp2f(st1[u][1]);                         \
      const float b2 = __builtin_amdgcn_exp2f(st1[u][2]);                         \
      const float b3 = __builtin_amdgcn_exp2f(st1[u][3]);                         \
      lacc1 += (b0 + b1) + (b2 + b3);                                             \
      uint2v pk1;                                                                 \
      pk1.x = cvt_pk_bf16(b0, b1);                                                \
      pk1.y = cvt_pk_bf16(b2, b3);                                                \
      *(uint2v*)(Pw + pw_off[1][u]) = pk1;                                        \
    }                                                                             \
    {                                                                             \
      short8 pa00 = *(const short8*)(Pw + pa_off[0][0]);                          \
      short8 pa01 = *(const short8*)(Pw + pa_off[0][1]);                          \
      short8 pa10 = *(const short8*)(Pw + pa_off[1][0]);                          \
      short8 pa11 = *(const short8*)(Pw + pa_off[1][1]);                          \
      __builtin_amdgcn_s_setprio(1);                                              \
      _Pragma("unroll") for (int dn = 0; dn < 4; ++dn) {                          \
        const short8 vb0 = *(const short8*)(Vl + vb_off[dn][0]);                  \
        const short8 vb1 = *(const short8*)(Vl + vb_off[dn][1]);                  \
        o0[dn] = __builtin_amdgcn_mfma_f32_16x16x32_bf16(pa00, vb0, o0[dn], 0, 0, 0); \
        o0[dn] = __builtin_amdgcn_mfma_f32_16x16x32_bf16(pa01, vb1, o0[dn], 0, 0, 0); \
        o1[dn] = __builtin_amdgcn_mfma_f32_16x16x32_bf16(pa10, vb0, o1[dn], 0, 0, 0); \
        o1[dn] = __builtin_amdgcn_mfma_f32_16x16x32_bf16(pa11, vb1, o1[dn], 0, 0, 0); \
      }                                                                           \
      __builtin_amdgcn_s_setprio(0);                                              \
    }                                                                             \
    __syncthreads();                                                              \
  }

  for (int seg = 0; seg < 2; ++seg) {
    const int tile = seg ? pair : 31 - pair;      // long tile first, short second
    const int q0 = tile << 6;
    const int qw = q0 + w * 32;                   // wave's first q row (2 frags)
    const int nst = tile + 1;

    short8 qf[2][2];
#pragma unroll
    for (int f = 0; f < 2; ++f)
#pragma unroll
      for (int c = 0; c < 2; ++c)
        qf[f][c] = *(const short8*)(Qp + (size_t)(qw + f * 16 + lr) * HDIM + c * 32 + lg * 8);

    f32x4 o0[4] = {}, o1[4] = {};
    float lacc0 = 0.f, lacc1 = 0.f;

    STAGE(0, 0);
    __syncthreads();

    int kvt = 0;
    for (; kvt + 2 <= nst; kvt += 2) {
      STEP(0, kvt);
      STEP(1, kvt + 1);
    }
    if (kvt < nst) STEP(0, kvt);

    float rs0 = lacc0, rs1 = lacc1;
    rs0 += __shfl_xor(rs0, 16);
    rs0 += __shfl_xor(rs0, 32);
    rs1 += __shfl_xor(rs1, 16);
    rs1 += __shfl_xor(rs1, 32);
    float li0[4], li1[4];
#pragma unroll
    for (int j = 0; j < 4; ++j) {
      li0[j] = 1.0f / __shfl(rs0, (lg << 2) + j);
      li1[j] = 1.0f / __shfl(rs1, (lg << 2) + j);
    }
#pragma unroll
    for (int dn = 0; dn < 4; ++dn)
#pragma unroll
      for (int j = 0; j < 4; ++j) {
        const int col = h * 64 + dn * 16 + lr;
        const int m0 = b * NS + qw + (lg << 2) + j;
        Ob[(size_t)m0 * ND + col] = f2bf(o0[dn][j] * li0[j]);
        const int m1 = b * NS + qw + 16 + (lg << 2) + j;
        Ob[(size_t)m1 * ND + col] = f2bf(o1[dn][j] * li1[j]);
      }
  }
}

extern "C" void kernel_launch(void* const* d_in, const int* in_sizes, int n_in,
                              void* d_out, int out_size, void* d_ws, size_t ws_size,
                              hipStream_t stream) {
  const float* x  = (const float*)d_in[0];
  const float* fc = (const float*)d_in[1];
  const float* fs = (const float*)d_in[2];
  const float* Wq = (const float*)d_in[3];
  const float* Wk = (const float*)d_in[4];
  const float* Wv = (const float*)d_in[5];
  const float* Wo = (const float*)d_in[6];
  float* out = (float*)d_out;
  char* ws = (char*)d_ws;

  // Workspace timeline (40 MB):
  //  0- 8MB: xb (dead after gemm_qkv) -> VT
  //  8-14MB: WTqkv     14-16MB: WTo (written upfront, read at end)
  // 16-24MB: Qb        24-32MB: Kb
  // 32-40MB: Vb (dead after transpose_v) -> Ob
  u16* xb    = (u16*)(ws);
  u16* VT    = (u16*)(ws);
  u16* WTqkv = (u16*)(ws + (size_t)(8u << 20));
  u16* WTo   = (u16*)(ws + (size_t)(14u << 20));
  u16* Qb    = (u16*)(ws + (size_t)(16u << 20));
  u16* Kb    = (u16*)(ws + (size_t)(24u << 20));
  u16* Vb    = (u16*)(ws + (size_t)(32u << 20));
  u16* Ob    = Vb;

  cvt_x<<<4096, 256, 0, stream>>>(x, xb);
  transpose_w4<<<dim3(32, 32, 4), dim3(32, 8), 0, stream>>>(Wq, Wk, Wv, Wo, WTqkv, WTo);
  gemm64<4, 0><<<dim3(24, 32), 256, 0, stream>>>(xb, WTqkv, Qb, Kb, Vb, nullptr);
  rope_k<<<2048, 256, 0, stream>>>(Qb, Kb, fc, fs);
  transpose_v<<<dim3(32, 32), 256, 0, stream>>>(Vb, VT);
  attn_k<<<512, 128, 0, stream>>>(Qb, Kb, VT, Ob);
  gemm64<2, 1><<<dim3(8, 64), 256, 0, stream>>>(Ob, WTo, nullptr, nullptr, nullptr, out);
}

// Round 12
// 114.309 us; speedup vs baseline: 1.0824x; 1.0824x over previous
//
#include <hip/hip_runtime.h>
#include <stdint.h>

typedef unsigned short u16;
typedef __attribute__((ext_vector_type(8))) short short8;
typedef __attribute__((ext_vector_type(4))) short short4v;
typedef __attribute__((ext_vector_type(4))) float f32x4;
typedef __attribute__((ext_vector_type(4))) unsigned short ushort4v;
typedef __attribute__((ext_vector_type(2))) unsigned int uint2v;

#define NB 2
#define NS 2048
#define ND 1024
#define NH 16
#define HDIM 64
#define NHALF 32
#define QSCALE 0.18033688f   /* 0.125 * log2(e) : folds 1/sqrt(64) and exp->exp2 */
#define NEGBIG -3.0e38f      /* finite "-inf": exp2 -> 0, no NaN from arithmetic */

__device__ __forceinline__ float bf2f(u16 u) {
  union { unsigned u; float f; } v; v.u = ((unsigned)u) << 16; return v.f;
}
__device__ __forceinline__ u16 f2bf(float f) {
  union { float f; unsigned u; } v; v.f = f;
  unsigned r = v.u + 0x7fffu + ((v.u >> 16) & 1u);
  return (u16)(r >> 16);
}

// packs lo->bits[15:0], hi->bits[31:16], RNE — same rounding as f2bf
__device__ __forceinline__ unsigned cvt_pk_bf16(float lo, float hi) {
  unsigned r;
  asm("v_cvt_pk_bf16_f32 %0, %1, %2" : "=v"(r) : "v"(lo), "v"(hi));
  return r;
}

__device__ __forceinline__ void gld_lds16(const u16* g, u16* l) {
  void* gv = (void*)g;
  __builtin_amdgcn_global_load_lds((__attribute__((address_space(1))) void*)gv,
                                   (__attribute__((address_space(3))) void*)l, 16, 0, 0);
}

// ---------------- convert x (fp32 -> bf16) ----------------
__global__ void cvt_x(const float* __restrict__ x, u16* __restrict__ xb) {
  int i = blockIdx.x * 256 + threadIdx.x;
  float4 v = ((const float4*)x)[i];
  ushort4v o;
  o.x = f2bf(v.x); o.y = f2bf(v.y); o.z = f2bf(v.z); o.w = f2bf(v.w);
  ((ushort4v*)xb)[i] = o;
}

// ---------------- transpose + convert all 4 weights (z = 0..3) ----------------
__global__ void transpose_w4(const float* __restrict__ W0, const float* __restrict__ W1,
                             const float* __restrict__ W2, const float* __restrict__ W3,
                             u16* __restrict__ dqkv, u16* __restrict__ dout) {
  __shared__ float tile[32][33];
  const int z = blockIdx.z;
  const float* W = (z == 0) ? W0 : (z == 1) ? W1 : (z == 2) ? W2 : W3;
  u16* dst = (z < 3) ? (dqkv + (size_t)z * ND * ND) : dout;
  const int n0 = blockIdx.x * 32, k0 = blockIdx.y * 32;
  const int tx = threadIdx.x, ty = threadIdx.y;
#pragma unroll
  for (int i = 0; i < 4; ++i)
    tile[ty + i * 8][tx] = W[(size_t)(k0 + ty + i * 8) * ND + n0 + tx];
  __syncthreads();
#pragma unroll
  for (int i = 0; i < 4; ++i)
    dst[(size_t)(n0 + ty + i * 8) * ND + k0 + tx] = f2bf(tile[tx][ty + i * 8]);
}

// ---------------- unified GEMM, BK=64, XOR-swizzled LDS (proven R10) ----------------
// MODE 0: Q,K -> [b][h][s][d] scatter; V -> VT [b][h][d][s] DIRECT (8B packed
// stores, 4 consecutive s per lane) — transpose_v kernel eliminated.
// MODE 1: fp32 rows into fo.
template<int MI, int MODE>
__global__ __launch_bounds__(256) void gemm64(
    const u16* __restrict__ A, const u16* __restrict__ BT,
    u16* __restrict__ qo, u16* __restrict__ ko, u16* __restrict__ vo,
    float* __restrict__ fo) {
  __shared__ u16 smem[MI * 2048 + 8192];   // A[(MI*32)][64] | B[128][64]
  const int tid = threadIdx.x;
  const int w = tid >> 6, lane = tid & 63;
  const int lr = lane & 15, lg = lane >> 4;
  const int bm = blockIdx.y * (MI * 32), bn = blockIdx.x << 7;
  const int wr = (w >> 1) * (MI * 16), wc = (w & 1) << 6;
  f32x4 acc[MI][4] = {};

  const int arow = tid >> 3;
  const int aslot = (tid & 7) ^ (arow & 7);
  const u16* ags = A + (size_t)(bm + arow) * ND + (aslot << 3);
  const u16* bgs = BT + (size_t)(bn + arow) * ND + (aslot << 3);
  u16* const As = smem;
  u16* const Bs = smem + MI * 2048;

  int af_off[MI][2], bf_off[4][2];
#pragma unroll
  for (int mi = 0; mi < MI; ++mi)
#pragma unroll
    for (int kk = 0; kk < 2; ++kk)
      af_off[mi][kk] = (wr + mi * 16 + lr) * 64 + ((((kk << 2) + lg) ^ (lr & 7)) << 3);
#pragma unroll
  for (int ni = 0; ni < 4; ++ni)
#pragma unroll
    for (int kk = 0; kk < 2; ++kk)
      bf_off[ni][kk] = (wc + ni * 16 + lr) * 64 + ((((kk << 2) + lg) ^ (lr & 7)) << 3);

  for (int kt = 0; kt < ND; kt += 64) {
#pragma unroll
    for (int it = 0; it < MI; ++it)
      gld_lds16(ags + it * (32 * ND) + kt, As + it * 2048 + w * 512);
#pragma unroll
    for (int it = 0; it < 4; ++it)
      gld_lds16(bgs + it * (32 * ND) + kt, Bs + it * 2048 + w * 512);
    __syncthreads();
#pragma unroll
    for (int kk = 0; kk < 2; ++kk) {
      short8 af[MI], bfr[4];
#pragma unroll
      for (int mi = 0; mi < MI; ++mi)
        af[mi] = *(const short8*)(As + af_off[mi][kk]);
#pragma unroll
      for (int ni = 0; ni < 4; ++ni)
        bfr[ni] = *(const short8*)(Bs + bf_off[ni][kk]);
#pragma unroll
      for (int mi = 0; mi < MI; ++mi)
#pragma unroll
        for (int ni = 0; ni < 4; ++ni)
          acc[mi][ni] = __builtin_amdgcn_mfma_f32_16x16x32_bf16(af[mi], bfr[ni], acc[mi][ni], 0, 0, 0);
    }
    __syncthreads();
  }

  if (MODE == 0) {
#pragma unroll
    for (int mi = 0; mi < MI; ++mi) {
#pragma unroll
      for (int ni = 0; ni < 4; ++ni) {
        const int n = bn + wc + ni * 16 + lr;
        const int which = n >> 10, hh = (n >> 6) & 15, d = n & 63;
        if (which == 2) {
          // V -> VT [b][h][d][s]: 4 consecutive s per lane, one 8B store
          const int m0 = bm + wr + mi * 16 + (lg << 2);
          const int b = m0 >> 11, s0 = m0 & 2047;
          uint2v pk;
          pk.x = cvt_pk_bf16(acc[mi][ni][0], acc[mi][ni][1]);
          pk.y = cvt_pk_bf16(acc[mi][ni][2], acc[mi][ni][3]);
          *(uint2v*)(vo + ((size_t)(b * NH + hh) * HDIM + d) * NS + s0) = pk;
        } else {
          u16* dst = which == 0 ? qo : ko;
#pragma unroll
          for (int j = 0; j < 4; ++j) {
            const int m = bm + wr + mi * 16 + (lg << 2) + j;
            const int b = m >> 11, s = m & 2047;
            dst[(((size_t)(b * NH + hh) * NS + s) << 6) + d] = f2bf(acc[mi][ni][j]);
          }
        }
      }
    }
  } else {
#pragma unroll
    for (int mi = 0; mi < MI; ++mi)
#pragma unroll
      for (int ni = 0; ni < 4; ++ni)
#pragma unroll
        for (int j = 0; j < 4; ++j) {
          const int m = bm + wr + mi * 16 + (lg << 2) + j;
          const int n = bn + wc + ni * 16 + lr;
          fo[(size_t)m * ND + n] = acc[mi][ni][j];
        }
  }
}

// ---------------- RoPE on Q,K in place (vectorized); Q pre-scaled ----------------
__global__ void rope_k(u16* __restrict__ Qb, u16* __restrict__ Kb,
                       const float* __restrict__ cosT, const float* __restrict__ sinT) {
  int t = blockIdx.x * 256 + threadIdx.x;   // B*H*S*8 threads, 8 bf16 each
  int g = t & 7;
  int s = (t >> 3) & 2047;
  int bh = t >> 14;
  float4 c4 = *(const float4*)(cosT + s * NHALF + (g << 2));
  float4 s4 = *(const float4*)(sinT + s * NHALF + (g << 2));
  size_t off = (((size_t)bh * NS + s) << 6) + (g << 3);
  short8 q = *(const short8*)(Qb + off);
  short8 k = *(const short8*)(Kb + off);
  float cc[4] = {c4.x, c4.y, c4.z, c4.w}, ss[4] = {s4.x, s4.y, s4.z, s4.w};
  short8 qo, ko;
#pragma unroll
  for (int p = 0; p < 4; ++p) {
    float q0 = bf2f((u16)q[2 * p]), q1 = bf2f((u16)q[2 * p + 1]);
    qo[2 * p]     = (short)f2bf((q0 * cc[p] - q1 * ss[p]) * QSCALE);
    qo[2 * p + 1] = (short)f2bf((q0 * ss[p] + q1 * cc[p]) * QSCALE);
    float k0 = bf2f((u16)k[2 * p]), k1 = bf2f((u16)k[2 * p + 1]);
    ko[2 * p]     = (short)f2bf(k0 * cc[p] - k1 * ss[p]);
    ko[2 * p + 1] = (short)f2bf(k0 * ss[p] + k1 * cc[p]);
  }
  *(short8*)(Qb + off) = qo;
  *(short8*)(Kb + off) = ko;
}

// ---------------- flash attention (causal), paired q-tiles (R8 proven) ----------------
// grid 512; block does q-tiles (31-pair) then (pair): 33 kv-steps uniform.
// 256 thr = 4 waves, 16 q-rows/wave; 2 blocks/CU, 2 waves/SIMD.
__global__ __launch_bounds__(256, 4) void attn_k(
    const u16* __restrict__ Qb, const u16* __restrict__ Kb,
    const u16* __restrict__ VT, u16* __restrict__ Ob) {
  __shared__ u16 K2[2][4096];   // [kv][d], rows 128B, XOR-swizzled
  __shared__ u16 V2[2][4096];   // [d][kv], rows 128B, XOR-swizzled
  __shared__ u16 Pl[4][1024];   // per wave [q=16][kv=64], rows 128B, XOR-swizzled
  const int tid = threadIdx.x, w = tid >> 6, lane = tid & 63;
  const int lr = lane & 15, lg = lane >> 4;
  const int bid = blockIdx.x;
  const int xcd = bid & 7, i = bid >> 3;          // i in 0..63
  const int bh = xcd * 4 + (i & 3);
  const int pair = i >> 2;                        // 0..15
  const int b = bh >> 4, h = bh & 15;
  const u16* Qp = Qb + (size_t)bh * NS * HDIM;
  const u16* Kp = Kb + (size_t)bh * NS * HDIM;
  const u16* Vp = VT + (size_t)bh * NS * HDIM;    // [d][s]

  int kf_off[4][2], vb_off[4][2], pw_off[4], pa_off[2];
#pragma unroll
  for (int u = 0; u < 4; ++u) {
    const int kvr = (u << 4) + lr;
#pragma unroll
    for (int c = 0; c < 2; ++c)
      kf_off[u][c] = kvr * 64 + ((((c << 6) + (lg << 4)) ^ ((kvr & 7) << 4)) >> 1);
  }
#pragma unroll
  for (int dn = 0; dn < 4; ++dn) {
    const int d = (dn << 4) + lr;
#pragma unroll
    for (int ks = 0; ks < 2; ++ks)
      vb_off[dn][ks] = d * 64 + ((((ks << 6) + (lg << 4)) ^ ((d & 7) << 4)) >> 1);
  }
#pragma unroll
  for (int u = 0; u < 4; ++u)
    pw_off[u] = lr * 64 + ((((u << 5) + (lg << 3)) ^ ((lr & 7) << 4)) >> 1);
#pragma unroll
  for (int ks = 0; ks < 2; ++ks)
    pa_off[ks] = lr * 64 + ((((ks << 6) + (lg << 4)) ^ ((lr & 7) << 4)) >> 1);
  u16* Pw = &Pl[w][0];

  const int rr = tid >> 3, slot = tid & 7;
  const int soff = (((slot << 4) ^ ((rr & 7) << 4)) >> 1);
  const u16* kg0 = Kp + rr * HDIM + soff;
  const u16* kg1 = Kp + (rr + 32) * HDIM + soff;
  const u16* vg0 = Vp + (size_t)rr * NS + soff;
  const u16* vg1 = Vp + (size_t)(rr + 32) * NS + soff;

#define STAGE(BUFI, KV0)                                         \
  {                                                              \
    gld_lds16(kg0 + (KV0) * HDIM, &K2[BUFI][w * 512]);           \
    gld_lds16(kg1 + (KV0) * HDIM, &K2[BUFI][(4 + w) * 512]);     \
    gld_lds16(vg0 + (KV0),        &V2[BUFI][w * 512]);           \
    gld_lds16(vg1 + (KV0),        &V2[BUFI][(4 + w) * 512]);     \
  }

#define STEP(BUF, KVT)                                                            \
  {                                                                               \
    const int kv0 = (KVT) << 6;                                                   \
    if ((KVT) + 1 < nst) STAGE(BUF ^ 1, kv0 + 64);                                \
    const u16* Kl = K2[BUF];                                                      \
    const u16* Vl = V2[BUF];                                                      \
    f32x4 st[4] = {};                                                             \
    __builtin_amdgcn_s_setprio(1);                                                \
    _Pragma("unroll") for (int u = 0; u < 4; ++u)                                 \
      _Pragma("unroll") for (int c = 0; c < 2; ++c)                               \
        st[u] = __builtin_amdgcn_mfma_f32_16x16x32_bf16(                          \
            *(const short8*)(Kl + kf_off[u][c]), qf[c], st[u], 0, 0, 0);          \
    __builtin_amdgcn_s_setprio(0);                                                \
    if (kv0 + 63 > qw) {                                                          \
      _Pragma("unroll") for (int u = 0; u < 4; ++u)                               \
        _Pragma("unroll") for (int j = 0; j < 4; ++j) {                           \
          const int kvg = kv0 + (u << 4) + (lg << 2) + j;                         \
          if (kvg > q_col) st[u][j] = NEGBIG;                                     \
        }                                                                         \
    }                                                                             \
    _Pragma("unroll") for (int u = 0; u < 4; ++u) {                               \
      const float e0 = __builtin_amdgcn_exp2f(st[u][0]);                          \
      const float e1 = __builtin_amdgcn_exp2f(st[u][1]);                          \
      const float e2 = __builtin_amdgcn_exp2f(st[u][2]);                          \
      const float e3 = __builtin_amdgcn_exp2f(st[u][3]);                          \
      lacc += (e0 + e1) + (e2 + e3);                                              \
      uint2v pk;                                                                  \
      pk.x = cvt_pk_bf16(e0, e1);                                                 \
      pk.y = cvt_pk_bf16(e2, e3);                                                 \
      *(uint2v*)(Pw + pw_off[u]) = pk;                                            \
    }                                                                             \
    {                                                                             \
      short8 pa0 = *(const short8*)(Pw + pa_off[0]);                              \
      short8 pa1 = *(const short8*)(Pw + pa_off[1]);                              \
      __builtin_amdgcn_s_setprio(1);                                              \
      _Pragma("unroll") for (int dn = 0; dn < 4; ++dn) {                          \
        o[dn] = __builtin_amdgcn_mfma_f32_16x16x32_bf16(                          \
            pa0, *(const short8*)(Vl + vb_off[dn][0]), o[dn], 0, 0, 0);           \
        o[dn] = __builtin_amdgcn_mfma_f32_16x16x32_bf16(                          \
            pa1, *(const short8*)(Vl + vb_off[dn][1]), o[dn], 0, 0, 0);           \
      }                                                                           \
      __builtin_amdgcn_s_setprio(0);                                              \
    }                                                                             \
    __syncthreads();                                                              \
  }

  for (int seg = 0; seg < 2; ++seg) {
    const int tile = seg ? pair : 31 - pair;      // long tile first, short second
    const int q0 = tile << 6;
    const int qw = q0 + w * 16;
    const int q_col = qw + lr;
    const int nst = tile + 1;

    short8 qf[2];
#pragma unroll
    for (int c = 0; c < 2; ++c)
      qf[c] = *(const short8*)(Qp + (size_t)(qw + lr) * HDIM + c * 32 + lg * 8);

    f32x4 o[4] = {};
    float lacc = 0.f;

    STAGE(0, 0);
    __syncthreads();

    int kvt = 0;
    for (; kvt + 2 <= nst; kvt += 2) {
      STEP(0, kvt);
      STEP(1, kvt + 1);
    }
    if (kvt < nst) STEP(0, kvt);

    float rs = lacc;
    rs += __shfl_xor(rs, 16);
    rs += __shfl_xor(rs, 32);
    float li[4];
#pragma unroll
    for (int j = 0; j < 4; ++j) li[j] = 1.0f / __shfl(rs, (lg << 2) + j);
#pragma unroll
    for (int dn = 0; dn < 4; ++dn)
#pragma unroll
      for (int j = 0; j < 4; ++j) {
        const int m = b * NS + qw + (lg << 2) + j;
        const int col = h * 64 + dn * 16 + lr;
        Ob[(size_t)m * ND + col] = f2bf(o[dn][j] * li[j]);
      }
  }
}

extern "C" void kernel_launch(void* const* d_in, const int* in_sizes, int n_in,
                              void* d_out, int out_size, void* d_ws, size_t ws_size,
                              hipStream_t stream) {
  const float* x  = (const float*)d_in[0];
  const float* fc = (const float*)d_in[1];
  const float* fs = (const float*)d_in[2];
  const float* Wq = (const float*)d_in[3];
  const float* Wk = (const float*)d_in[4];
  const float* Wv = (const float*)d_in[5];
  const float* Wo = (const float*)d_in[6];
  float* out = (float*)d_out;
  char* ws = (char*)d_ws;

  // Workspace timeline (40 MB):
  //  0- 8MB: xb (dead after gemm_qkv) -> Ob
  //  8-14MB: WTqkv     14-16MB: WTo (written upfront, read at end)
  // 16-24MB: Qb        24-32MB: Kb
  // 32-40MB: VT (written DIRECTLY by gemm_qkv V-epilogue; no Vb, no transpose_v)
  u16* xb    = (u16*)(ws);
  u16* Ob    = (u16*)(ws);
  u16* WTqkv = (u16*)(ws + (size_t)(8u << 20));
  u16* WTo   = (u16*)(ws + (size_t)(14u << 20));
  u16* Qb    = (u16*)(ws + (size_t)(16u << 20));
  u16* Kb    = (u16*)(ws + (size_t)(24u << 20));
  u16* VT    = (u16*)(ws + (size_t)(32u << 20));

  cvt_x<<<4096, 256, 0, stream>>>(x, xb);
  transpose_w4<<<dim3(32, 32, 4), dim3(32, 8), 0, stream>>>(Wq, Wk, Wv, Wo, WTqkv, WTo);
  gemm64<4, 0><<<dim3(24, 32), 256, 0, stream>>>(xb, WTqkv, Qb, Kb, VT, nullptr);
  rope_k<<<2048, 256, 0, stream>>>(Qb, Kb, fc, fs);
  attn_k<<<512, 256, 0, stream>>>(Qb, Kb, VT, Ob);
  gemm64<2, 1><<<dim3(8, 64), 256, 0, stream>>>(Ob, WTo, nullptr, nullptr, nullptr, out);
}

// Round 13
// 109.116 us; speedup vs baseline: 1.1339x; 1.0476x over previous
//
#include <hip/hip_runtime.h>
#include <stdint.h>

typedef unsigned short u16;
typedef __attribute__((ext_vector_type(8))) short short8;
typedef __attribute__((ext_vector_type(4))) float f32x4;
typedef __attribute__((ext_vector_type(4))) unsigned short ushort4v;
typedef __attribute__((ext_vector_type(2))) unsigned int uint2v;

#define NB 2
#define NS 2048
#define ND 1024
#define NH 16
#define HDIM 64
#define NHALF 32
#define QSCALE 0.18033688f   /* 0.125 * log2(e) : folds 1/sqrt(64) and exp->exp2 */
#define NEGBIG -3.0e38f      /* finite "-inf": exp2 -> 0, no NaN from arithmetic */

__device__ __forceinline__ float bf2f(u16 u) {
  union { unsigned u; float f; } v; v.u = ((unsigned)u) << 16; return v.f;
}
__device__ __forceinline__ u16 f2bf(float f) {
  union { float f; unsigned u; } v; v.f = f;
  unsigned r = v.u + 0x7fffu + ((v.u >> 16) & 1u);
  return (u16)(r >> 16);
}

// packs lo->bits[15:0], hi->bits[31:16], RNE — same rounding as f2bf
__device__ __forceinline__ unsigned cvt_pk_bf16(float lo, float hi) {
  unsigned r;
  asm("v_cvt_pk_bf16_f32 %0, %1, %2" : "=v"(r) : "v"(lo), "v"(hi));
  return r;
}

__device__ __forceinline__ void gld_lds16(const u16* g, u16* l) {
  void* gv = (void*)g;
  __builtin_amdgcn_global_load_lds((__attribute__((address_space(1))) void*)gv,
                                   (__attribute__((address_space(3))) void*)l, 16, 0, 0);
}

// ---------------- convert x (fp32 -> bf16) ----------------
__global__ void cvt_x(const float* __restrict__ x, u16* __restrict__ xb) {
  int i = blockIdx.x * 256 + threadIdx.x;
  float4 v = ((const float4*)x)[i];
  ushort4v o;
  o.x = f2bf(v.x); o.y = f2bf(v.y); o.z = f2bf(v.z); o.w = f2bf(v.w);
  ((ushort4v*)xb)[i] = o;
}

// ---------------- transpose + convert all 4 weights (z = 0..3) ----------------
__global__ void transpose_w4(const float* __restrict__ W0, const float* __restrict__ W1,
                             const float* __restrict__ W2, const float* __restrict__ W3,
                             u16* __restrict__ dqkv, u16* __restrict__ dout) {
  __shared__ float tile[32][33];
  const int z = blockIdx.z;
  const float* W = (z == 0) ? W0 : (z == 1) ? W1 : (z == 2) ? W2 : W3;
  u16* dst = (z < 3) ? (dqkv + (size_t)z * ND * ND) : dout;
  const int n0 = blockIdx.x * 32, k0 = blockIdx.y * 32;
  const int tx = threadIdx.x, ty = threadIdx.y;
#pragma unroll
  for (int i = 0; i < 4; ++i)
    tile[ty + i * 8][tx] = W[(size_t)(k0 + ty + i * 8) * ND + n0 + tx];
  __syncthreads();
#pragma unroll
  for (int i = 0; i < 4; ++i)
    dst[(size_t)(n0 + ty + i * 8) * ND + k0 + tx] = f2bf(tile[tx][ty + i * 8]);
}

// ---------------- unified GEMM, BK=64, XOR-swizzled + double-buffered LDS ----------------
// One barrier per K-step: STAGE(next buf) issued BEFORE ds_read+MFMA(cur buf);
// the barrier's vmcnt drain happens after a full compute phase (T3 2-phase).
// MODE 0 (QK): operand-SWAPPED MFMA -> acc holds (x@W)^T fragments: lane owns
//   4 consecutive d at fixed s = 2 RoPE pairs -> RoPE+QSCALE fused, 8B stores.
//   rope_k kernel eliminated.
// MODE 1 (V):  normal orientation, direct VT [b][h][d][s] 8B packed stores.
// MODE 2 (out): fp32 rows.
template<int MI, int MODE>
__global__ __launch_bounds__(256) void gemm64(
    const u16* __restrict__ A, const u16* __restrict__ BT,
    u16* __restrict__ qo, u16* __restrict__ ko, u16* __restrict__ vo,
    float* __restrict__ fo,
    const float* __restrict__ cosT, const float* __restrict__ sinT) {
  __shared__ u16 smem[2][MI * 2048 + 8192];   // per buf: A[(MI*32)][64] | B[128][64]
  const int tid = threadIdx.x;
  const int w = tid >> 6, lane = tid & 63;
  const int lr = lane & 15, lg = lane >> 4;
  const int bm = blockIdx.y * (MI * 32), bn = blockIdx.x << 7;
  const int wr = (w >> 1) * (MI * 16), wc = (w & 1) << 6;
  f32x4 acc[MI][4] = {};

  const int arow = tid >> 3;
  const int aslot = (tid & 7) ^ (arow & 7);
  const u16* ags = A + (size_t)(bm + arow) * ND + (aslot << 3);
  const u16* bgs = BT + (size_t)(bn + arow) * ND + (aslot << 3);

  int af_off[MI][2], bf_off[4][2];
#pragma unroll
  for (int mi = 0; mi < MI; ++mi)
#pragma unroll
    for (int kk = 0; kk < 2; ++kk)
      af_off[mi][kk] = (wr + mi * 16 + lr) * 64 + ((((kk << 2) + lg) ^ (lr & 7)) << 3);
#pragma unroll
  for (int ni = 0; ni < 4; ++ni)
#pragma unroll
    for (int kk = 0; kk < 2; ++kk)
      bf_off[ni][kk] = (wc + ni * 16 + lr) * 64 + ((((kk << 2) + lg) ^ (lr & 7)) << 3);

#define GSTAGE(BUF, KT)                                                     \
  {                                                                         \
    _Pragma("unroll")                                                       \
    for (int it = 0; it < MI; ++it)                                         \
      gld_lds16(ags + it * (32 * ND) + (KT), &smem[BUF][it * 2048 + w * 512]); \
    _Pragma("unroll")                                                       \
    for (int it = 0; it < 4; ++it)                                          \
      gld_lds16(bgs + it * (32 * ND) + (KT), &smem[BUF][MI * 2048 + it * 2048 + w * 512]); \
  }

  GSTAGE(0, 0);
  __syncthreads();
  int cur = 0;
  for (int kt = 0; kt < ND; kt += 64) {
    if (kt + 64 < ND) GSTAGE(cur ^ 1, kt + 64);
    const u16* As = smem[cur];
    const u16* Bs = smem[cur] + MI * 2048;
#pragma unroll
    for (int kk = 0; kk < 2; ++kk) {
      short8 af[MI], bfr[4];
#pragma unroll
      for (int mi = 0; mi < MI; ++mi)
        af[mi] = *(const short8*)(As + af_off[mi][kk]);
#pragma unroll
      for (int ni = 0; ni < 4; ++ni)
        bfr[ni] = *(const short8*)(Bs + bf_off[ni][kk]);
#pragma unroll
      for (int mi = 0; mi < MI; ++mi)
#pragma unroll
        for (int ni = 0; ni < 4; ++ni) {
          if (MODE == 0)   // swapped operands: acc = (x@W)^T fragment
            acc[mi][ni] = __builtin_amdgcn_mfma_f32_16x16x32_bf16(bfr[ni], af[mi], acc[mi][ni], 0, 0, 0);
          else
            acc[mi][ni] = __builtin_amdgcn_mfma_f32_16x16x32_bf16(af[mi], bfr[ni], acc[mi][ni], 0, 0, 0);
        }
    }
    __syncthreads();
    cur ^= 1;
  }

  if (MODE == 0) {
    // acc[mi][ni][j]: row = n = bn+wc+ni*16+(lg<<2)+j (d-dim), col = s = bm+wr+mi*16+lr
#pragma unroll
    for (int mi = 0; mi < MI; ++mi) {
      const int m = bm + wr + mi * 16 + lr;
      const int b = m >> 11, s = m & 2047;
      const float* cbase = cosT + s * NHALF;
      const float* sbase = sinT + s * NHALF;
#pragma unroll
      for (int ni = 0; ni < 4; ++ni) {
        const int n = bn + wc + ni * 16 + (lg << 2);
        const int which = n >> 10, hh = (n >> 6) & 15, d0 = n & 63;
        u16* dst = which == 0 ? qo : ko;
        const float sc = which == 0 ? QSCALE : 1.0f;
        const float2 cp = *(const float2*)(cbase + (d0 >> 1));
        const float2 sp = *(const float2*)(sbase + (d0 >> 1));
        const float v0 = acc[mi][ni][0], v1 = acc[mi][ni][1];
        const float v2 = acc[mi][ni][2], v3 = acc[mi][ni][3];
        uint2v pk;
        pk.x = cvt_pk_bf16((v0 * cp.x - v1 * sp.x) * sc, (v0 * sp.x + v1 * cp.x) * sc);
        pk.y = cvt_pk_bf16((v2 * cp.y - v3 * sp.y) * sc, (v2 * sp.y + v3 * cp.y) * sc);
        *(uint2v*)(dst + (((size_t)(b * NH + hh) * NS + s) << 6) + d0) = pk;
      }
    }
  } else if (MODE == 1) {
    // normal orientation: lane holds 4 consecutive s at fixed d -> VT[b][h][d][s]
#pragma unroll
    for (int mi = 0; mi < MI; ++mi) {
#pragma unroll
      for (int ni = 0; ni < 4; ++ni) {
        const int n = bn + wc + ni * 16 + lr;         // d-index in [0,1024)
        const int hh = n >> 6, d = n & 63;
        const int m0 = bm + wr + mi * 16 + (lg << 2);
        const int b = m0 >> 11, s0 = m0 & 2047;
        uint2v pk;
        pk.x = cvt_pk_bf16(acc[mi][ni][0], acc[mi][ni][1]);
        pk.y = cvt_pk_bf16(acc[mi][ni][2], acc[mi][ni][3]);
        *(uint2v*)(vo + ((size_t)(b * NH + hh) * HDIM + d) * NS + s0) = pk;
      }
    }
  } else {
#pragma unroll
    for (int mi = 0; mi < MI; ++mi)
#pragma unroll
      for (int ni = 0; ni < 4; ++ni)
#pragma unroll
        for (int j = 0; j < 4; ++j) {
          const int m = bm + wr + mi * 16 + (lg << 2) + j;
          const int n = bn + wc + ni * 16 + lr;
          fo[(size_t)m * ND + n] = acc[mi][ni][j];
        }
  }
}

// ---------------- flash attention (causal), paired q-tiles (R8 proven) ----------------
__global__ __launch_bounds__(256, 4) void attn_k(
    const u16* __restrict__ Qb, const u16* __restrict__ Kb,
    const u16* __restrict__ VT, u16* __restrict__ Ob) {
  __shared__ u16 K2[2][4096];   // [kv][d], rows 128B, XOR-swizzled
  __shared__ u16 V2[2][4096];   // [d][kv], rows 128B, XOR-swizzled
  __shared__ u16 Pl[4][1024];   // per wave [q=16][kv=64], rows 128B, XOR-swizzled
  const int tid = threadIdx.x, w = tid >> 6, lane = tid & 63;
  const int lr = lane & 15, lg = lane >> 4;
  const int bid = blockIdx.x;
  const int xcd = bid & 7, i = bid >> 3;          // i in 0..63
  const int bh = xcd * 4 + (i & 3);
  const int pair = i >> 2;                        // 0..15
  const int b = bh >> 4, h = bh & 15;
  const u16* Qp = Qb + (size_t)bh * NS * HDIM;
  const u16* Kp = Kb + (size_t)bh * NS * HDIM;
  const u16* Vp = VT + (size_t)bh * NS * HDIM;    // [d][s]

  int kf_off[4][2], vb_off[4][2], pw_off[4], pa_off[2];
#pragma unroll
  for (int u = 0; u < 4; ++u) {
    const int kvr = (u << 4) + lr;
#pragma unroll
    for (int c = 0; c < 2; ++c)
      kf_off[u][c] = kvr * 64 + ((((c << 6) + (lg << 4)) ^ ((kvr & 7) << 4)) >> 1);
  }
#pragma unroll
  for (int dn = 0; dn < 4; ++dn) {
    const int d = (dn << 4) + lr;
#pragma unroll
    for (int ks = 0; ks < 2; ++ks)
      vb_off[dn][ks] = d * 64 + ((((ks << 6) + (lg << 4)) ^ ((d & 7) << 4)) >> 1);
  }
#pragma unroll
  for (int u = 0; u < 4; ++u)
    pw_off[u] = lr * 64 + ((((u << 5) + (lg << 3)) ^ ((lr & 7) << 4)) >> 1);
#pragma unroll
  for (int ks = 0; ks < 2; ++ks)
    pa_off[ks] = lr * 64 + ((((ks << 6) + (lg << 4)) ^ ((lr & 7) << 4)) >> 1);
  u16* Pw = &Pl[w][0];

  const int rr = tid >> 3, slot = tid & 7;
  const int soff = (((slot << 4) ^ ((rr & 7) << 4)) >> 1);
  const u16* kg0 = Kp + rr * HDIM + soff;
  const u16* kg1 = Kp + (rr + 32) * HDIM + soff;
  const u16* vg0 = Vp + (size_t)rr * NS + soff;
  const u16* vg1 = Vp + (size_t)(rr + 32) * NS + soff;

#define STAGE(BUFI, KV0)                                         \
  {                                                              \
    gld_lds16(kg0 + (KV0) * HDIM, &K2[BUFI][w * 512]);           \
    gld_lds16(kg1 + (KV0) * HDIM, &K2[BUFI][(4 + w) * 512]);     \
    gld_lds16(vg0 + (KV0),        &V2[BUFI][w * 512]);           \
    gld_lds16(vg1 + (KV0),        &V2[BUFI][(4 + w) * 512]);     \
  }

#define STEP(BUF, KVT)                                                            \
  {                                                                               \
    const int kv0 = (KVT) << 6;                                                   \
    if ((KVT) + 1 < nst) STAGE(BUF ^ 1, kv0 + 64);                                \
    const u16* Kl = K2[BUF];                                                      \
    const u16* Vl = V2[BUF];                                                      \
    f32x4 st[4] = {};                                                             \
    __builtin_amdgcn_s_setprio(1);                                                \
    _Pragma("unroll") for (int u = 0; u < 4; ++u)                                 \
      _Pragma("unroll") for (int c = 0; c < 2; ++c)                               \
        st[u] = __builtin_amdgcn_mfma_f32_16x16x32_bf16(                          \
            *(const short8*)(Kl + kf_off[u][c]), qf[c], st[u], 0, 0, 0);          \
    __builtin_amdgcn_s_setprio(0);                                                \
    if (kv0 + 63 > qw) {                                                          \
      _Pragma("unroll") for (int u = 0; u < 4; ++u)                               \
        _Pragma("unroll") for (int j = 0; j < 4; ++j) {                           \
          const int kvg = kv0 + (u << 4) + (lg << 2) + j;                         \
          if (kvg > q_col) st[u][j] = NEGBIG;                                     \
        }                                                                         \
    }                                                                             \
    _Pragma("unroll") for (int u = 0; u < 4; ++u) {                               \
      const float e0 = __builtin_amdgcn_exp2f(st[u][0]);                          \
      const float e1 = __builtin_amdgcn_exp2f(st[u][1]);                          \
      const float e2 = __builtin_amdgcn_exp2f(st[u][2]);                          \
      const float e3 = __builtin_amdgcn_exp2f(st[u][3]);                          \
      lacc += (e0 + e1) + (e2 + e3);                                              \
      uint2v pk;                                                                  \
      pk.x = cvt_pk_bf16(e0, e1);                                                 \
      pk.y = cvt_pk_bf16(e2, e3);                                                 \
      *(uint2v*)(Pw + pw_off[u]) = pk;                                            \
    }                                                                             \
    {                                                                             \
      short8 pa0 = *(const short8*)(Pw + pa_off[0]);                              \
      short8 pa1 = *(const short8*)(Pw + pa_off[1]);                              \
      __builtin_amdgcn_s_setprio(1);                                              \
      _Pragma("unroll") for (int dn = 0; dn < 4; ++dn) {                          \
        o[dn] = __builtin_amdgcn_mfma_f32_16x16x32_bf16(                          \
            pa0, *(const short8*)(Vl + vb_off[dn][0]), o[dn], 0, 0, 0);           \
        o[dn] = __builtin_amdgcn_mfma_f32_16x16x32_bf16(                          \
            pa1, *(const short8*)(Vl + vb_off[dn][1]), o[dn], 0, 0, 0);           \
      }                                                                           \
      __builtin_amdgcn_s_setprio(0);                                              \
    }                                                                             \
    __syncthreads();                                                              \
  }

  for (int seg = 0; seg < 2; ++seg) {
    const int tile = seg ? pair : 31 - pair;      // long tile first, short second
    const int q0 = tile << 6;
    const int qw = q0 + w * 16;
    const int q_col = qw + lr;
    const int nst = tile + 1;

    short8 qf[2];
#pragma unroll
    for (int c = 0; c < 2; ++c)
      qf[c] = *(const short8*)(Qp + (size_t)(qw + lr) * HDIM + c * 32 + lg * 8);

    f32x4 o[4] = {};
    float lacc = 0.f;

    STAGE(0, 0);
    __syncthreads();

    int kvt = 0;
    for (; kvt + 2 <= nst; kvt += 2) {
      STEP(0, kvt);
      STEP(1, kvt + 1);
    }
    if (kvt < nst) STEP(0, kvt);

    float rs = lacc;
    rs += __shfl_xor(rs, 16);
    rs += __shfl_xor(rs, 32);
    float li[4];
#pragma unroll
    for (int j = 0; j < 4; ++j) li[j] = 1.0f / __shfl(rs, (lg << 2) + j);
#pragma unroll
    for (int dn = 0; dn < 4; ++dn)
#pragma unroll
      for (int j = 0; j < 4; ++j) {
        const int m = b * NS + qw + (lg << 2) + j;
        const int col = h * 64 + dn * 16 + lr;
        Ob[(size_t)m * ND + col] = f2bf(o[dn][j] * li[j]);
      }
  }
}

extern "C" void kernel_launch(void* const* d_in, const int* in_sizes, int n_in,
                              void* d_out, int out_size, void* d_ws, size_t ws_size,
                              hipStream_t stream) {
  const float* x  = (const float*)d_in[0];
  const float* fc = (const float*)d_in[1];
  const float* fs = (const float*)d_in[2];
  const float* Wq = (const float*)d_in[3];
  const float* Wk = (const float*)d_in[4];
  const float* Wv = (const float*)d_in[5];
  const float* Wo = (const float*)d_in[6];
  float* out = (float*)d_out;
  char* ws = (char*)d_ws;

  // Workspace timeline (40 MB):
  //  0- 8MB: xb (dead after gemms) -> Ob
  //  8-14MB: WTqkv     14-16MB: WTo (written upfront, read at end)
  // 16-24MB: Qb        24-32MB: Kb
  // 32-40MB: VT (written DIRECTLY by V-gemm epilogue)
  u16* xb    = (u16*)(ws);
  u16* Ob    = (u16*)(ws);
  u16* WTqkv = (u16*)(ws + (size_t)(8u << 20));
  u16* WTo   = (u16*)(ws + (size_t)(14u << 20));
  u16* Qb    = (u16*)(ws + (size_t)(16u << 20));
  u16* Kb    = (u16*)(ws + (size_t)(24u << 20));
  u16* VT    = (u16*)(ws + (size_t)(32u << 20));
  u16* WTv   = WTqkv + (size_t)2 * ND * ND;

  cvt_x<<<4096, 256, 0, stream>>>(x, xb);
  transpose_w4<<<dim3(32, 32, 4), dim3(32, 8), 0, stream>>>(Wq, Wk, Wv, Wo, WTqkv, WTo);
  // QK projection with fused RoPE (swapped-operand epilogue): N = 2048 (q|k)
  gemm64<4, 0><<<dim3(16, 32), 256, 0, stream>>>(xb, WTqkv, Qb, Kb, nullptr, nullptr, fc, fs);
  // V projection -> VT direct: N = 1024
  gemm64<4, 1><<<dim3(8, 32), 256, 0, stream>>>(xb, WTv, nullptr, nullptr, VT, nullptr, nullptr, nullptr);
  attn_k<<<512, 256, 0, stream>>>(Qb, Kb, VT, Ob);
  gemm64<2, 2><<<dim3(8, 64), 256, 0, stream>>>(Ob, WTo, nullptr, nullptr, nullptr, out, nullptr, nullptr);
}

// Round 14
// 102.080 us; speedup vs baseline: 1.2121x; 1.0689x over previous
//
#include <hip/hip_runtime.h>
#include <stdint.h>

typedef unsigned short u16;
typedef __attribute__((ext_vector_type(8))) short short8;
typedef __attribute__((ext_vector_type(4))) float f32x4;
typedef __attribute__((ext_vector_type(4))) unsigned short ushort4v;
typedef __attribute__((ext_vector_type(2))) unsigned int uint2v;

#define NB 2
#define NS 2048
#define ND 1024
#define NH 16
#define HDIM 64
#define NHALF 32
#define QSCALE 0.18033688f   /* 0.125 * log2(e) : folds 1/sqrt(64) and exp->exp2 */
#define NEGBIG -3.0e38f      /* finite "-inf": exp2 -> 0, no NaN from arithmetic */

__device__ __forceinline__ float bf2f(u16 u) {
  union { unsigned u; float f; } v; v.u = ((unsigned)u) << 16; return v.f;
}
__device__ __forceinline__ u16 f2bf(float f) {
  union { float f; unsigned u; } v; v.f = f;
  unsigned r = v.u + 0x7fffu + ((v.u >> 16) & 1u);
  return (u16)(r >> 16);
}

// packs lo->bits[15:0], hi->bits[31:16], RNE — same rounding as f2bf
__device__ __forceinline__ unsigned cvt_pk_bf16(float lo, float hi) {
  unsigned r;
  asm("v_cvt_pk_bf16_f32 %0, %1, %2" : "=v"(r) : "v"(lo), "v"(hi));
  return r;
}

__device__ __forceinline__ void gld_lds16(const u16* g, u16* l) {
  void* gv = (void*)g;
  __builtin_amdgcn_global_load_lds((__attribute__((address_space(1))) void*)gv,
                                   (__attribute__((address_space(3))) void*)l, 16, 0, 0);
}

// ---------------- prep: cvt_x (blocks 0..4095) + transpose_w4 (4096..8191) ----------------
__global__ void prep(const float* __restrict__ x, u16* __restrict__ xb,
                     const float* __restrict__ W0, const float* __restrict__ W1,
                     const float* __restrict__ W2, const float* __restrict__ W3,
                     u16* __restrict__ dqkv, u16* __restrict__ dout) {
  __shared__ float tile[32][33];
  const int bid = blockIdx.x;
  if (bid < 4096) {
    int i = bid * 256 + threadIdx.x;
    float4 v = ((const float4*)x)[i];
    ushort4v o;
    o.x = f2bf(v.x); o.y = f2bf(v.y); o.z = f2bf(v.z); o.w = f2bf(v.w);
    ((ushort4v*)xb)[i] = o;
  } else {
    int idx = bid - 4096;
    const int z = idx >> 10;
    idx &= 1023;
    const int bx = idx & 31, by = idx >> 5;
    const float* W = (z == 0) ? W0 : (z == 1) ? W1 : (z == 2) ? W2 : W3;
    u16* dst = (z < 3) ? (dqkv + (size_t)z * ND * ND) : dout;
    const int n0 = bx * 32, k0 = by * 32;
    const int tx = threadIdx.x & 31, ty = threadIdx.x >> 5;   // 32x8
#pragma unroll
    for (int i = 0; i < 4; ++i)
      tile[ty + i * 8][tx] = W[(size_t)(k0 + ty + i * 8) * ND + n0 + tx];
    __syncthreads();
#pragma unroll
    for (int i = 0; i < 4; ++i)
      dst[(size_t)(n0 + ty + i * 8) * ND + k0 + tx] = f2bf(tile[tx][ty + i * 8]);
  }
}

// ---------------- unified GEMM, BK=64, XOR-swizzled + double-buffered LDS ----------------
// One barrier per K-step: STAGE(next buf) issued BEFORE ds_read+MFMA(cur buf).
// MODE 0 (QK): operand-SWAPPED MFMA -> acc holds (x@W)^T fragments: lane owns
//   4 consecutive d at fixed s = 2 RoPE pairs -> RoPE+QSCALE fused, 8B stores.
// MODE 1 (V):  normal orientation, direct VT [b][h][d][s] 8B packed stores.
// MODE 2 (out): fp32 rows.
template<int MI, int MODE>
__global__ __launch_bounds__(256) void gemm64(
    const u16* __restrict__ A, const u16* __restrict__ BT,
    u16* __restrict__ qo, u16* __restrict__ ko, u16* __restrict__ vo,
    float* __restrict__ fo,
    const float* __restrict__ cosT, const float* __restrict__ sinT) {
  __shared__ u16 smem[2][MI * 2048 + 8192];   // per buf: A[(MI*32)][64] | B[128][64]
  const int tid = threadIdx.x;
  const int w = tid >> 6, lane = tid & 63;
  const int lr = lane & 15, lg = lane >> 4;
  const int bm = blockIdx.y * (MI * 32), bn = blockIdx.x << 7;
  const int wr = (w >> 1) * (MI * 16), wc = (w & 1) << 6;
  f32x4 acc[MI][4] = {};

  const int arow = tid >> 3;
  const int aslot = (tid & 7) ^ (arow & 7);
  const u16* ags = A + (size_t)(bm + arow) * ND + (aslot << 3);
  const u16* bgs = BT + (size_t)(bn + arow) * ND + (aslot << 3);

  int af_off[MI][2], bf_off[4][2];
#pragma unroll
  for (int mi = 0; mi < MI; ++mi)
#pragma unroll
    for (int kk = 0; kk < 2; ++kk)
      af_off[mi][kk] = (wr + mi * 16 + lr) * 64 + ((((kk << 2) + lg) ^ (lr & 7)) << 3);
#pragma unroll
  for (int ni = 0; ni < 4; ++ni)
#pragma unroll
    for (int kk = 0; kk < 2; ++kk)
      bf_off[ni][kk] = (wc + ni * 16 + lr) * 64 + ((((kk << 2) + lg) ^ (lr & 7)) << 3);

#define GSTAGE(BUF, KT)                                                     \
  {                                                                         \
    _Pragma("unroll")                                                       \
    for (int it = 0; it < MI; ++it)                                         \
      gld_lds16(ags + it * (32 * ND) + (KT), &smem[BUF][it * 2048 + w * 512]); \
    _Pragma("unroll")                                                       \
    for (int it = 0; it < 4; ++it)                                          \
      gld_lds16(bgs + it * (32 * ND) + (KT), &smem[BUF][MI * 2048 + it * 2048 + w * 512]); \
  }

  GSTAGE(0, 0);
  __syncthreads();
  int cur = 0;
  for (int kt = 0; kt < ND; kt += 64) {
    if (kt + 64 < ND) GSTAGE(cur ^ 1, kt + 64);
    const u16* As = smem[cur];
    const u16* Bs = smem[cur] + MI * 2048;
#pragma unroll
    for (int kk = 0; kk < 2; ++kk) {
      short8 af[MI], bfr[4];
#pragma unroll
      for (int mi = 0; mi < MI; ++mi)
        af[mi] = *(const short8*)(As + af_off[mi][kk]);
#pragma unroll
      for (int ni = 0; ni < 4; ++ni)
        bfr[ni] = *(const short8*)(Bs + bf_off[ni][kk]);
#pragma unroll
      for (int mi = 0; mi < MI; ++mi)
#pragma unroll
        for (int ni = 0; ni < 4; ++ni) {
          if (MODE == 0)   // swapped operands: acc = (x@W)^T fragment
            acc[mi][ni] = __builtin_amdgcn_mfma_f32_16x16x32_bf16(bfr[ni], af[mi], acc[mi][ni], 0, 0, 0);
          else
            acc[mi][ni] = __builtin_amdgcn_mfma_f32_16x16x32_bf16(af[mi], bfr[ni], acc[mi][ni], 0, 0, 0);
        }
    }
    __syncthreads();
    cur ^= 1;
  }

  if (MODE == 0) {
    // acc[mi][ni][j]: row = n = bn+wc+ni*16+(lg<<2)+j (d-dim), col = s = bm+wr+mi*16+lr
#pragma unroll
    for (int mi = 0; mi < MI; ++mi) {
      const int m = bm + wr + mi * 16 + lr;
      const int b = m >> 11, s = m & 2047;
      const float* cbase = cosT + s * NHALF;
      const float* sbase = sinT + s * NHALF;
#pragma unroll
      for (int ni = 0; ni < 4; ++ni) {
        const int n = bn + wc + ni * 16 + (lg << 2);
        const int which = n >> 10, hh = (n >> 6) & 15, d0 = n & 63;
        u16* dst = which == 0 ? qo : ko;
        const float sc = which == 0 ? QSCALE : 1.0f;
        const float2 cp = *(const float2*)(cbase + (d0 >> 1));
        const float2 sp = *(const float2*)(sbase + (d0 >> 1));
        const float v0 = acc[mi][ni][0], v1 = acc[mi][ni][1];
        const float v2 = acc[mi][ni][2], v3 = acc[mi][ni][3];
        uint2v pk;
        pk.x = cvt_pk_bf16((v0 * cp.x - v1 * sp.x) * sc, (v0 * sp.x + v1 * cp.x) * sc);
        pk.y = cvt_pk_bf16((v2 * cp.y - v3 * sp.y) * sc, (v2 * sp.y + v3 * cp.y) * sc);
        *(uint2v*)(dst + (((size_t)(b * NH + hh) * NS + s) << 6) + d0) = pk;
      }
    }
  } else if (MODE == 1) {
    // normal orientation: lane holds 4 consecutive s at fixed d -> VT[b][h][d][s]
#pragma unroll
    for (int mi = 0; mi < MI; ++mi) {
#pragma unroll
      for (int ni = 0; ni < 4; ++ni) {
        const int n = bn + wc + ni * 16 + lr;         // d-index in [0,1024)
        const int hh = n >> 6, d = n & 63;
        const int m0 = bm + wr + mi * 16 + (lg << 2);
        const int b = m0 >> 11, s0 = m0 & 2047;
        uint2v pk;
        pk.x = cvt_pk_bf16(acc[mi][ni][0], acc[mi][ni][1]);
        pk.y = cvt_pk_bf16(acc[mi][ni][2], acc[mi][ni][3]);
        *(uint2v*)(vo + ((size_t)(b * NH + hh) * HDIM + d) * NS + s0) = pk;
      }
    }
  } else {
#pragma unroll
    for (int mi = 0; mi < MI; ++mi)
#pragma unroll
      for (int ni = 0; ni < 4; ++ni)
#pragma unroll
        for (int j = 0; j < 4; ++j) {
          const int m = bm + wr + mi * 16 + (lg << 2) + j;
          const int n = bn + wc + ni * 16 + lr;
          fo[(size_t)m * ND + n] = acc[mi][ni][j];
        }
  }
}

// ---------------- flash attention (causal), paired q-tiles (R8 proven) ----------------
__global__ __launch_bounds__(256, 4) void attn_k(
    const u16* __restrict__ Qb, const u16* __restrict__ Kb,
    const u16* __restrict__ VT, u16* __restrict__ Ob) {
  __shared__ u16 K2[2][4096];   // [kv][d], rows 128B, XOR-swizzled
  __shared__ u16 V2[2][4096];   // [d][kv], rows 128B, XOR-swizzled
  __shared__ u16 Pl[4][1024];   // per wave [q=16][kv=64], rows 128B, XOR-swizzled
  const int tid = threadIdx.x, w = tid >> 6, lane = tid & 63;
  const int lr = lane & 15, lg = lane >> 4;
  const int bid = blockIdx.x;
  const int xcd = bid & 7, i = bid >> 3;          // i in 0..63
  const int bh = xcd * 4 + (i & 3);
  const int pair = i >> 2;                        // 0..15
  const int b = bh >> 4, h = bh & 15;
  const u16* Qp = Qb + (size_t)bh * NS * HDIM;
  const u16* Kp = Kb + (size_t)bh * NS * HDIM;
  const u16* Vp = VT + (size_t)bh * NS * HDIM;    // [d][s]

  int kf_off[4][2], vb_off[4][2], pw_off[4], pa_off[2];
#pragma unroll
  for (int u = 0; u < 4; ++u) {
    const int kvr = (u << 4) + lr;
#pragma unroll
    for (int c = 0; c < 2; ++c)
      kf_off[u][c] = kvr * 64 + ((((c << 6) + (lg << 4)) ^ ((kvr & 7) << 4)) >> 1);
  }
#pragma unroll
  for (int dn = 0; dn < 4; ++dn) {
    const int d = (dn << 4) + lr;
#pragma unroll
    for (int ks = 0; ks < 2; ++ks)
      vb_off[dn][ks] = d * 64 + ((((ks << 6) + (lg << 4)) ^ ((d & 7) << 4)) >> 1);
  }
#pragma unroll
  for (int u = 0; u < 4; ++u)
    pw_off[u] = lr * 64 + ((((u << 5) + (lg << 3)) ^ ((lr & 7) << 4)) >> 1);
#pragma unroll
  for (int ks = 0; ks < 2; ++ks)
    pa_off[ks] = lr * 64 + ((((ks << 6) + (lg << 4)) ^ ((lr & 7) << 4)) >> 1);
  u16* Pw = &Pl[w][0];

  const int rr = tid >> 3, slot = tid & 7;
  const int soff = (((slot << 4) ^ ((rr & 7) << 4)) >> 1);
  const u16* kg0 = Kp + rr * HDIM + soff;
  const u16* kg1 = Kp + (rr + 32) * HDIM + soff;
  const u16* vg0 = Vp + (size_t)rr * NS + soff;
  const u16* vg1 = Vp + (size_t)(rr + 32) * NS + soff;

#define STAGE(BUFI, KV0)                                         \
  {                                                              \
    gld_lds16(kg0 + (KV0) * HDIM, &K2[BUFI][w * 512]);           \
    gld_lds16(kg1 + (KV0) * HDIM, &K2[BUFI][(4 + w) * 512]);     \
    gld_lds16(vg0 + (KV0),        &V2[BUFI][w * 512]);           \
    gld_lds16(vg1 + (KV0),        &V2[BUFI][(4 + w) * 512]);     \
  }

#define STEP(BUF, KVT)                                                            \
  {                                                                               \
    const int kv0 = (KVT) << 6;                                                   \
    if ((KVT) + 1 < nst) STAGE(BUF ^ 1, kv0 + 64);                                \
    const u16* Kl = K2[BUF];                                                      \
    const u16* Vl = V2[BUF];                                                      \
    f32x4 st[4] = {};                                                             \
    __builtin_amdgcn_s_setprio(1);                                                \
    _Pragma("unroll") for (int u = 0; u < 4; ++u)                                 \
      _Pragma("unroll") for (int c = 0; c < 2; ++c)                               \
        st[u] = __builtin_amdgcn_mfma_f32_16x16x32_bf16(                          \
            *(const short8*)(Kl + kf_off[u][c]), qf[c], st[u], 0, 0, 0);          \
    __builtin_amdgcn_s_setprio(0);                                                \
    if (kv0 + 63 > qw) {                                                          \
      _Pragma("unroll") for (int u = 0; u < 4; ++u)                               \
        _Pragma("unroll") for (int j = 0; j < 4; ++j) {                           \
          const int kvg = kv0 + (u << 4) + (lg << 2) + j;                         \
          if (kvg > q_col) st[u][j] = NEGBIG;                                     \
        }                                                                         \
    }                                                                             \
    _Pragma("unroll") for (int u = 0; u < 4; ++u) {                               \
      const float e0 = __builtin_amdgcn_exp2f(st[u][0]);                          \
      const float e1 = __builtin_amdgcn_exp2f(st[u][1]);                          \
      const float e2 = __builtin_amdgcn_exp2f(st[u][2]);                          \
      const float e3 = __builtin_amdgcn_exp2f(st[u][3]);                          \
      lacc += (e0 + e1) + (e2 + e3);                                              \
      uint2v pk;                                                                  \
      pk.x = cvt_pk_bf16(e0, e1);                                                 \
      pk.y = cvt_pk_bf16(e2, e3);                                                 \
      *(uint2v*)(Pw + pw_off[u]) = pk;                                            \
    }                                                                             \
    {                                                                             \
      short8 pa0 = *(const short8*)(Pw + pa_off[0]);                              \
      short8 pa1 = *(const short8*)(Pw + pa_off[1]);                              \
      __builtin_amdgcn_s_setprio(1);                                              \
      _Pragma("unroll") for (int dn = 0; dn < 4; ++dn) {                          \
        o[dn] = __builtin_amdgcn_mfma_f32_16x16x32_bf16(                          \
            pa0, *(const short8*)(Vl + vb_off[dn][0]), o[dn], 0, 0, 0);           \
        o[dn] = __builtin_amdgcn_mfma_f32_16x16x32_bf16(                          \
            pa1, *(const short8*)(Vl + vb_off[dn][1]), o[dn], 0, 0, 0);           \
      }                                                                           \
      __builtin_amdgcn_s_setprio(0);                                              \
    }                                                                             \
    __syncthreads();                                                              \
  }

  for (int seg = 0; seg < 2; ++seg) {
    const int tile = seg ? pair : 31 - pair;      // long tile first, short second
    const int q0 = tile << 6;
    const int qw = q0 + w * 16;
    const int q_col = qw + lr;
    const int nst = tile + 1;

    short8 qf[2];
#pragma unroll
    for (int c = 0; c < 2; ++c)
      qf[c] = *(const short8*)(Qp + (size_t)(qw + lr) * HDIM + c * 32 + lg * 8);

    f32x4 o[4] = {};
    float lacc = 0.f;

    STAGE(0, 0);
    __syncthreads();

    int kvt = 0;
    for (; kvt + 2 <= nst; kvt += 2) {
      STEP(0, kvt);
      STEP(1, kvt + 1);
    }
    if (kvt < nst) STEP(0, kvt);

    float rs = lacc;
    rs += __shfl_xor(rs, 16);
    rs += __shfl_xor(rs, 32);
    float li[4];
#pragma unroll
    for (int j = 0; j < 4; ++j) li[j] = 1.0f / __shfl(rs, (lg << 2) + j);
#pragma unroll
    for (int dn = 0; dn < 4; ++dn)
#pragma unroll
      for (int j = 0; j < 4; ++j) {
        const int m = b * NS + qw + (lg << 2) + j;
        const int col = h * 64 + dn * 16 + lr;
        Ob[(size_t)m * ND + col] = f2bf(o[dn][j] * li[j]);
      }
  }
}

extern "C" void kernel_launch(void* const* d_in, const int* in_sizes, int n_in,
                              void* d_out, int out_size, void* d_ws, size_t ws_size,
                              hipStream_t stream) {
  const float* x  = (const float*)d_in[0];
  const float* fc = (const float*)d_in[1];
  const float* fs = (const float*)d_in[2];
  const float* Wq = (const float*)d_in[3];
  const float* Wk = (const float*)d_in[4];
  const float* Wv = (const float*)d_in[5];
  const float* Wo = (const float*)d_in[6];
  float* out = (float*)d_out;
  char* ws = (char*)d_ws;

  // Workspace timeline (40 MB):
  //  0- 8MB: xb (dead after gemms) -> Ob
  //  8-14MB: WTqkv     14-16MB: WTo (written upfront, read at end)
  // 16-24MB: Qb        24-32MB: Kb
  // 32-40MB: VT (written DIRECTLY by V-gemm epilogue)
  u16* xb    = (u16*)(ws);
  u16* Ob    = (u16*)(ws);
  u16* WTqkv = (u16*)(ws + (size_t)(8u << 20));
  u16* WTo   = (u16*)(ws + (size_t)(14u << 20));
  u16* Qb    = (u16*)(ws + (size_t)(16u << 20));
  u16* Kb    = (u16*)(ws + (size_t)(24u << 20));
  u16* VT    = (u16*)(ws + (size_t)(32u << 20));
  u16* WTv   = WTqkv + (size_t)2 * ND * ND;

  prep<<<8192, 256, 0, stream>>>(x, xb, Wq, Wk, Wv, Wo, WTqkv, WTo);
  // QK projection with fused RoPE (swapped-operand epilogue): N = 2048 (q|k)
  gemm64<4, 0><<<dim3(16, 32), 256, 0, stream>>>(xb, WTqkv, Qb, Kb, nullptr, nullptr, fc, fs);
  // V projection -> VT direct: N = 1024, MI=2 -> 512 blocks (2 blocks/CU)
  gemm64<2, 1><<<dim3(8, 64), 256, 0, stream>>>(xb, WTv, nullptr, nullptr, VT, nullptr, nullptr, nullptr);
  attn_k<<<512, 256, 0, stream>>>(Qb, Kb, VT, Ob);
  gemm64<2, 2><<<dim3(8, 64), 256, 0, stream>>>(Ob, WTo, nullptr, nullptr, nullptr, out, nullptr, nullptr);
}

// Round 15
// 101.873 us; speedup vs baseline: 1.2146x; 1.0020x over previous
//
#include <hip/hip_runtime.h>
#include <stdint.h>

typedef unsigned short u16;
typedef __attribute__((ext_vector_type(8))) short short8;
typedef __attribute__((ext_vector_type(4))) float f32x4;
typedef __attribute__((ext_vector_type(4))) unsigned short ushort4v;
typedef __attribute__((ext_vector_type(2))) unsigned int uint2v;

#define NB 2
#define NS 2048
#define ND 1024
#define NH 16
#define HDIM 64
#define NHALF 32
#define QSCALE 0.18033688f   /* 0.125 * log2(e) : folds 1/sqrt(64) and exp->exp2 */
#define NEGBIG -3.0e38f      /* finite "-inf": exp2 -> 0, no NaN from arithmetic */

__device__ __forceinline__ float bf2f(u16 u) {
  union { unsigned u; float f; } v; v.u = ((unsigned)u) << 16; return v.f;
}
__device__ __forceinline__ u16 f2bf(float f) {
  union { float f; unsigned u; } v; v.f = f;
  unsigned r = v.u + 0x7fffu + ((v.u >> 16) & 1u);
  return (u16)(r >> 16);
}

// packs lo->bits[15:0], hi->bits[31:16], RNE — same rounding as f2bf
__device__ __forceinline__ unsigned cvt_pk_bf16(float lo, float hi) {
  unsigned r;
  asm("v_cvt_pk_bf16_f32 %0, %1, %2" : "=v"(r) : "v"(lo), "v"(hi));
  return r;
}

__device__ __forceinline__ void gld_lds16(const u16* g, u16* l) {
  void* gv = (void*)g;
  __builtin_amdgcn_global_load_lds((__attribute__((address_space(1))) void*)gv,
                                   (__attribute__((address_space(3))) void*)l, 16, 0, 0);
}

// ---------------- prep: cvt_x (blocks 0..4095) + transpose_w4 (4096..8191) ----------------
__global__ void prep(const float* __restrict__ x, u16* __restrict__ xb,
                     const float* __restrict__ W0, const float* __restrict__ W1,
                     const float* __restrict__ W2, const float* __restrict__ W3,
                     u16* __restrict__ dqkv, u16* __restrict__ dout) {
  __shared__ float tile[32][33];
  const int bid = blockIdx.x;
  if (bid < 4096) {
    int i = bid * 256 + threadIdx.x;
    float4 v = ((const float4*)x)[i];
    ushort4v o;
    o.x = f2bf(v.x); o.y = f2bf(v.y); o.z = f2bf(v.z); o.w = f2bf(v.w);
    ((ushort4v*)xb)[i] = o;
  } else {
    int idx = bid - 4096;
    const int z = idx >> 10;
    idx &= 1023;
    const int bx = idx & 31, by = idx >> 5;
    const float* W = (z == 0) ? W0 : (z == 1) ? W1 : (z == 2) ? W2 : W3;
    u16* dst = (z < 3) ? (dqkv + (size_t)z * ND * ND) : dout;
    const int n0 = bx * 32, k0 = by * 32;
    const int tx = threadIdx.x & 31, ty = threadIdx.x >> 5;   // 32x8
#pragma unroll
    for (int i = 0; i < 4; ++i)
      tile[ty + i * 8][tx] = W[(size_t)(k0 + ty + i * 8) * ND + n0 + tx];
    __syncthreads();
#pragma unroll
    for (int i = 0; i < 4; ++i)
      dst[(size_t)(n0 + ty + i * 8) * ND + k0 + tx] = f2bf(tile[tx][ty + i * 8]);
  }
}

// ---------------- shared GEMM body, BK=64, XOR-swizzled + double-buffered LDS ----------------
// MODE 0 (QK): operand-SWAPPED MFMA -> acc = (x@W)^T fragments: lane owns 4
//   consecutive d at fixed s -> RoPE+QSCALE fused, 8B stores.
// MODE 1 (V):  normal orientation, direct VT [b][h][d][s] 8B packed stores.
// MODE 2 (out): fp32 rows.
template<int MI, int MODE>
__device__ __forceinline__ void gemm_body(
    u16* smem0, int bx, int by,
    const u16* __restrict__ A, const u16* __restrict__ BT,
    u16* __restrict__ qo, u16* __restrict__ ko, u16* __restrict__ vo,
    float* __restrict__ fo,
    const float* __restrict__ cosT, const float* __restrict__ sinT) {
  constexpr int BUFSZ = MI * 2048 + 8192;
  const int tid = threadIdx.x;
  const int w = tid >> 6, lane = tid & 63;
  const int lr = lane & 15, lg = lane >> 4;
  const int bm = by * (MI * 32), bn = bx << 7;
  const int wr = (w >> 1) * (MI * 16), wc = (w & 1) << 6;
  f32x4 acc[MI][4] = {};

  const int arow = tid >> 3;
  const int aslot = (tid & 7) ^ (arow & 7);
  const u16* ags = A + (size_t)(bm + arow) * ND + (aslot << 3);
  const u16* bgs = BT + (size_t)(bn + arow) * ND + (aslot << 3);

  int af_off[MI][2], bf_off[4][2];
#pragma unroll
  for (int mi = 0; mi < MI; ++mi)
#pragma unroll
    for (int kk = 0; kk < 2; ++kk)
      af_off[mi][kk] = (wr + mi * 16 + lr) * 64 + ((((kk << 2) + lg) ^ (lr & 7)) << 3);
#pragma unroll
  for (int ni = 0; ni < 4; ++ni)
#pragma unroll
    for (int kk = 0; kk < 2; ++kk)
      bf_off[ni][kk] = (wc + ni * 16 + lr) * 64 + ((((kk << 2) + lg) ^ (lr & 7)) << 3);

  auto stage = [&](int buf, int kt) {
    u16* dst = smem0 + buf * BUFSZ;
#pragma unroll
    for (int it = 0; it < MI; ++it)
      gld_lds16(ags + it * (32 * ND) + kt, dst + it * 2048 + w * 512);
#pragma unroll
    for (int it = 0; it < 4; ++it)
      gld_lds16(bgs + it * (32 * ND) + kt, dst + MI * 2048 + it * 2048 + w * 512);
  };

  stage(0, 0);
  __syncthreads();
  int cur = 0;
  for (int kt = 0; kt < ND; kt += 64) {
    if (kt + 64 < ND) stage(cur ^ 1, kt + 64);
    const u16* As = smem0 + cur * BUFSZ;
    const u16* Bs = As + MI * 2048;
#pragma unroll
    for (int kk = 0; kk < 2; ++kk) {
      short8 af[MI], bfr[4];
#pragma unroll
      for (int mi = 0; mi < MI; ++mi)
        af[mi] = *(const short8*)(As + af_off[mi][kk]);
#pragma unroll
      for (int ni = 0; ni < 4; ++ni)
        bfr[ni] = *(const short8*)(Bs + bf_off[ni][kk]);
#pragma unroll
      for (int mi = 0; mi < MI; ++mi)
#pragma unroll
        for (int ni = 0; ni < 4; ++ni) {
          if (MODE == 0)   // swapped operands: acc = (x@W)^T fragment
            acc[mi][ni] = __builtin_amdgcn_mfma_f32_16x16x32_bf16(bfr[ni], af[mi], acc[mi][ni], 0, 0, 0);
          else
            acc[mi][ni] = __builtin_amdgcn_mfma_f32_16x16x32_bf16(af[mi], bfr[ni], acc[mi][ni], 0, 0, 0);
        }
    }
    __syncthreads();
    cur ^= 1;
  }

  if (MODE == 0) {
    // acc[mi][ni][j]: row = n = bn+wc+ni*16+(lg<<2)+j (d-dim), col = s = bm+wr+mi*16+lr
#pragma unroll
    for (int mi = 0; mi < MI; ++mi) {
      const int m = bm + wr + mi * 16 + lr;
      const int b = m >> 11, s = m & 2047;
      const float* cbase = cosT + s * NHALF;
      const float* sbase = sinT + s * NHALF;
#pragma unroll
      for (int ni = 0; ni < 4; ++ni) {
        const int n = bn + wc + ni * 16 + (lg << 2);
        const int which = n >> 10, hh = (n >> 6) & 15, d0 = n & 63;
        u16* dst = which == 0 ? qo : ko;
        const float sc = which == 0 ? QSCALE : 1.0f;
        const float2 cp = *(const float2*)(cbase + (d0 >> 1));
        const float2 sp = *(const float2*)(sbase + (d0 >> 1));
        const float v0 = acc[mi][ni][0], v1 = acc[mi][ni][1];
        const float v2 = acc[mi][ni][2], v3 = acc[mi][ni][3];
        uint2v pk;
        pk.x = cvt_pk_bf16((v0 * cp.x - v1 * sp.x) * sc, (v0 * sp.x + v1 * cp.x) * sc);
        pk.y = cvt_pk_bf16((v2 * cp.y - v3 * sp.y) * sc, (v2 * sp.y + v3 * cp.y) * sc);
        *(uint2v*)(dst + (((size_t)(b * NH + hh) * NS + s) << 6) + d0) = pk;
      }
    }
  } else if (MODE == 1) {
    // normal orientation: lane holds 4 consecutive s at fixed d -> VT[b][h][d][s]
#pragma unroll
    for (int mi = 0; mi < MI; ++mi) {
#pragma unroll
      for (int ni = 0; ni < 4; ++ni) {
        const int n = bn + wc + ni * 16 + lr;         // d-index in [0,1024)
        const int hh = n >> 6, d = n & 63;
        const int m0 = bm + wr + mi * 16 + (lg << 2);
        const int b = m0 >> 11, s0 = m0 & 2047;
        uint2v pk;
        pk.x = cvt_pk_bf16(acc[mi][ni][0], acc[mi][ni][1]);
        pk.y = cvt_pk_bf16(acc[mi][ni][2], acc[mi][ni][3]);
        *(uint2v*)(vo + ((size_t)(b * NH + hh) * HDIM + d) * NS + s0) = pk;
      }
    }
  } else {
#pragma unroll
    for (int mi = 0; mi < MI; ++mi)
#pragma unroll
      for (int ni = 0; ni < 4; ++ni)
#pragma unroll
        for (int j = 0; j < 4; ++j) {
          const int m = bm + wr + mi * 16 + (lg << 2) + j;
          const int n = bn + wc + ni * 16 + lr;
          fo[(size_t)m * ND + n] = acc[mi][ni][j];
        }
  }
}

// Merged QKV projection: blocks 0..511 = QK (MI=4, fused RoPE), 512..1023 = V (MI=2 -> VT)
__global__ __launch_bounds__(256) void gemm_qkv(
    const u16* __restrict__ xb, const u16* __restrict__ WTqkv, const u16* __restrict__ WTv,
    u16* __restrict__ Qb, u16* __restrict__ Kb, u16* __restrict__ VT,
    const float* __restrict__ fc, const float* __restrict__ fs) {
  __shared__ u16 smem[2 * 16384];   // 64 KB: QK path 2x16384; V path uses 2x12288
  const int bid = blockIdx.x;
  if (bid < 512) {
    gemm_body<4, 0>(smem, bid & 15, bid >> 4, xb, WTqkv, Qb, Kb, nullptr, nullptr, fc, fs);
  } else {
    const int idx = bid - 512;
    gemm_body<2, 1>(smem, idx & 7, idx >> 3, xb, WTv, nullptr, nullptr, VT, nullptr, nullptr, nullptr);
  }
}

__global__ __launch_bounds__(256) void gemm_out_k(
    const u16* __restrict__ Ob, const u16* __restrict__ WTo, float* __restrict__ out) {
  __shared__ u16 smem[2 * 12288];
  gemm_body<2, 2>(smem, blockIdx.x, blockIdx.y, Ob, WTo, nullptr, nullptr, nullptr, out, nullptr, nullptr);
}

// ---------------- flash attention (causal), 8 waves x 128-row paired q-tiles ----------------
// grid 256 blocks of 512 thr; block does q-tiles (15-pair) then (pair) of 128
// rows: 34 kv-steps uniform. K/V LDS reads amortize over 2x the q-output vs
// the 4-wave version; STEP internals identical to the proven R8 code.
__global__ __launch_bounds__(512) void attn_k(
    const u16* __restrict__ Qb, const u16* __restrict__ Kb,
    const u16* __restrict__ VT, u16* __restrict__ Ob) {
  __shared__ u16 K2[2][4096];   // [kv=64][d=64], rows 128B, XOR-swizzled
  __shared__ u16 V2[2][4096];   // [d=64][kv=64], rows 128B, XOR-swizzled
  __shared__ u16 Pl[8][1024];   // per wave [q=16][kv=64], rows 128B, XOR-swizzled
  const int tid = threadIdx.x, w = tid >> 6, lane = tid & 63;
  const int lr = lane & 15, lg = lane >> 4;
  const int bid = blockIdx.x;
  const int xcd = bid & 7, i = bid >> 3;          // i in 0..31
  const int bh = xcd * 4 + (i & 3);
  const int pair = i >> 2;                        // 0..7
  const int b = bh >> 4, h = bh & 15;
  const u16* Qp = Qb + (size_t)bh * NS * HDIM;
  const u16* Kp = Kb + (size_t)bh * NS * HDIM;
  const u16* Vp = VT + (size_t)bh * NS * HDIM;    // [d][s]

  int kf_off[4][2], vb_off[4][2], pw_off[4], pa_off[2];
#pragma unroll
  for (int u = 0; u < 4; ++u) {
    const int kvr = (u << 4) + lr;
#pragma unroll
    for (int c = 0; c < 2; ++c)
      kf_off[u][c] = kvr * 64 + ((((c << 6) + (lg << 4)) ^ ((kvr & 7) << 4)) >> 1);
  }
#pragma unroll
  for (int dn = 0; dn < 4; ++dn) {
    const int d = (dn << 4) + lr;
#pragma unroll
    for (int ks = 0; ks < 2; ++ks)
      vb_off[dn][ks] = d * 64 + ((((ks << 6) + (lg << 4)) ^ ((d & 7) << 4)) >> 1);
  }
#pragma unroll
  for (int u = 0; u < 4; ++u)
    pw_off[u] = lr * 64 + ((((u << 5) + (lg << 3)) ^ ((lr & 7) << 4)) >> 1);
#pragma unroll
  for (int ks = 0; ks < 2; ++ks)
    pa_off[ks] = lr * 64 + ((((ks << 6) + (lg << 4)) ^ ((lr & 7) << 4)) >> 1);
  u16* Pw = &Pl[w][0];

  // staging: 512 threads cover the 8KB K tile + 8KB V tile in ONE instr each.
  // rr = tid>>3 = 8w + (lane>>3) rows; dest K2 + w*512 is linear per wave.
  const int rr = tid >> 3, slot = tid & 7;
  const int soff = ((slot ^ (rr & 7)) << 3);
  const u16* kg0 = Kp + (size_t)rr * HDIM + soff;
  const u16* vg0 = Vp + (size_t)rr * NS + soff;

#define STAGE(BUFI, KV0)                                   \
  {                                                        \
    gld_lds16(kg0 + (size_t)(KV0) * HDIM, &K2[BUFI][w * 512]); \
    gld_lds16(vg0 + (KV0),                &V2[BUFI][w * 512]); \
  }

#define STEP(BUF, KVT)                                                            \
  {                                                                               \
    const int kv0 = (KVT) << 6;                                                   \
    if ((KVT) + 1 < nst) STAGE(BUF ^ 1, kv0 + 64);                                \
    const u16* Kl = K2[BUF];                                                      \
    const u16* Vl = V2[BUF];                                                      \
    f32x4 st[4] = {};                                                             \
    __builtin_amdgcn_s_setprio(1);                                                \
    _Pragma("unroll") for (int u = 0; u < 4; ++u)                                 \
      _Pragma("unroll") for (int c = 0; c < 2; ++c)                               \
        st[u] = __builtin_amdgcn_mfma_f32_16x16x32_bf16(                          \
            *(const short8*)(Kl + kf_off[u][c]), qf[c], st[u], 0, 0, 0);          \
    __builtin_amdgcn_s_setprio(0);                                                \
    if (kv0 + 63 > qw) {                                                          \
      _Pragma("unroll") for (int u = 0; u < 4; ++u)                               \
        _Pragma("unroll") for (int j = 0; j < 4; ++j) {                           \
          const int kvg = kv0 + (u << 4) + (lg << 2) + j;                         \
          if (kvg > q_col) st[u][j] = NEGBIG;                                     \
        }                                                                         \
    }                                                                             \
    _Pragma("unroll") for (int u = 0; u < 4; ++u) {                               \
      const float e0 = __builtin_amdgcn_exp2f(st[u][0]);                          \
      const float e1 = __builtin_amdgcn_exp2f(st[u][1]);                          \
      const float e2 = __builtin_amdgcn_exp2f(st[u][2]);                          \
      const float e3 = __builtin_amdgcn_exp2f(st[u][3]);                          \
      lacc += (e0 + e1) + (e2 + e3);                                              \
      uint2v pk;                                                                  \
      pk.x = cvt_pk_bf16(e0, e1);                                                 \
      pk.y = cvt_pk_bf16(e2, e3);                                                 \
      *(uint2v*)(Pw + pw_off[u]) = pk;                                            \
    }                                                                             \
    {                                                                             \
      short8 pa0 = *(const short8*)(Pw + pa_off[0]);                              \
      short8 pa1 = *(const short8*)(Pw + pa_off[1]);                              \
      __builtin_amdgcn_s_setprio(1);                                              \
      _Pragma("unroll") for (int dn = 0; dn < 4; ++dn) {                          \
        o[dn] = __builtin_amdgcn_mfma_f32_16x16x32_bf16(                          \
            pa0, *(const short8*)(Vl + vb_off[dn][0]), o[dn], 0, 0, 0);           \
        o[dn] = __builtin_amdgcn_mfma_f32_16x16x32_bf16(                          \
            pa1, *(const short8*)(Vl + vb_off[dn][1]), o[dn], 0, 0, 0);           \
      }                                                                           \
      __builtin_amdgcn_s_setprio(0);                                              \
    }                                                                             \
    __syncthreads();                                                              \
  }

  for (int seg = 0; seg < 2; ++seg) {
    const int tile = seg ? pair : 15 - pair;      // long tile first, short second
    const int q0 = tile << 7;                     // 128-row q-tile
    const int qw = q0 + w * 16;                   // wave w owns 16 q rows
    const int q_col = qw + lr;
    const int nst = 2 * tile + 2;                 // always even

    short8 qf[2];
#pragma unroll
    for (int c = 0; c < 2; ++c)
      qf[c] = *(const short8*)(Qp + (size_t)(qw + lr) * HDIM + c * 32 + lg * 8);

    f32x4 o[4] = {};
    float lacc = 0.f;

    STAGE(0, 0);
    __syncthreads();

    for (int kvt = 0; kvt < nst; kvt += 2) {
      STEP(0, kvt);
      STEP(1, kvt + 1);
    }

    float rs = lacc;
    rs += __shfl_xor(rs, 16);
    rs += __shfl_xor(rs, 32);
    float li[4];
#pragma unroll
    for (int j = 0; j < 4; ++j) li[j] = 1.0f / __shfl(rs, (lg << 2) + j);
#pragma unroll
    for (int dn = 0; dn < 4; ++dn)
#pragma unroll
      for (int j = 0; j < 4; ++j) {
        const int m = b * NS + qw + (lg << 2) + j;
        const int col = h * 64 + dn * 16 + lr;
        Ob[(size_t)m * ND + col] = f2bf(o[dn][j] * li[j]);
      }
  }
}

extern "C" void kernel_launch(void* const* d_in, const int* in_sizes, int n_in,
                              void* d_out, int out_size, void* d_ws, size_t ws_size,
                              hipStream_t stream) {
  const float* x  = (const float*)d_in[0];
  const float* fc = (const float*)d_in[1];
  const float* fs = (const float*)d_in[2];
  const float* Wq = (const float*)d_in[3];
  const float* Wk = (const float*)d_in[4];
  const float* Wv = (const float*)d_in[5];
  const float* Wo = (const float*)d_in[6];
  float* out = (float*)d_out;
  char* ws = (char*)d_ws;

  // Workspace timeline (40 MB):
  //  0- 8MB: xb (dead after gemms) -> Ob
  //  8-14MB: WTqkv     14-16MB: WTo (written upfront, read at end)
  // 16-24MB: Qb        24-32MB: Kb
  // 32-40MB: VT (written DIRECTLY by V-gemm epilogue)
  u16* xb    = (u16*)(ws);
  u16* Ob    = (u16*)(ws);
  u16* WTqkv = (u16*)(ws + (size_t)(8u << 20));
  u16* WTo   = (u16*)(ws + (size_t)(14u << 20));
  u16* Qb    = (u16*)(ws + (size_t)(16u << 20));
  u16* Kb    = (u16*)(ws + (size_t)(24u << 20));
  u16* VT    = (u16*)(ws + (size_t)(32u << 20));
  u16* WTv   = WTqkv + (size_t)2 * ND * ND;

  prep<<<8192, 256, 0, stream>>>(x, xb, Wq, Wk, Wv, Wo, WTqkv, WTo);
  gemm_qkv<<<1024, 256, 0, stream>>>(xb, WTqkv, WTv, Qb, Kb, VT, fc, fs);
  attn_k<<<256, 512, 0, stream>>>(Qb, Kb, VT, Ob);
  gemm_out_k<<<dim3(8, 64), 256, 0, stream>>>(Ob, WTo, out);
}

// Round 16
// 100.009 us; speedup vs baseline: 1.2372x; 1.0186x over previous
//
#include <hip/hip_runtime.h>
#include <stdint.h>

typedef unsigned short u16;
typedef __attribute__((ext_vector_type(8))) short short8;
typedef __attribute__((ext_vector_type(4))) float f32x4;
typedef __attribute__((ext_vector_type(4))) unsigned short ushort4v;
typedef __attribute__((ext_vector_type(2))) unsigned int uint2v;

#define NB 2
#define NS 2048
#define ND 1024
#define NH 16
#define HDIM 64
#define NHALF 32
#define QSCALE 0.18033688f   /* 0.125 * log2(e) : folds 1/sqrt(64) and exp->exp2 */
#define NEGBIG -3.0e38f      /* finite "-inf": exp2 -> 0, no NaN from arithmetic */

__device__ __forceinline__ float bf2f(u16 u) {
  union { unsigned u; float f; } v; v.u = ((unsigned)u) << 16; return v.f;
}
__device__ __forceinline__ u16 f2bf(float f) {
  union { float f; unsigned u; } v; v.f = f;
  unsigned r = v.u + 0x7fffu + ((v.u >> 16) & 1u);
  return (u16)(r >> 16);
}

// packs lo->bits[15:0], hi->bits[31:16], RNE — same rounding as f2bf
__device__ __forceinline__ unsigned cvt_pk_bf16(float lo, float hi) {
  unsigned r;
  asm("v_cvt_pk_bf16_f32 %0, %1, %2" : "=v"(r) : "v"(lo), "v"(hi));
  return r;
}

__device__ __forceinline__ void gld_lds16(const u16* g, u16* l) {
  void* gv = (void*)g;
  __builtin_amdgcn_global_load_lds((__attribute__((address_space(1))) void*)gv,
                                   (__attribute__((address_space(3))) void*)l, 16, 0, 0);
}

// ---------------- prep: cvt_x (blocks 0..4095) + transpose_w4 (4096..8191) ----------------
__global__ void prep(const float* __restrict__ x, u16* __restrict__ xb,
                     const float* __restrict__ W0, const float* __restrict__ W1,
                     const float* __restrict__ W2, const float* __restrict__ W3,
                     u16* __restrict__ dqkv, u16* __restrict__ dout) {
  __shared__ float tile[32][33];
  const int bid = blockIdx.x;
  if (bid < 4096) {
    int i = bid * 256 + threadIdx.x;
    float4 v = ((const float4*)x)[i];
    ushort4v o;
    o.x = f2bf(v.x); o.y = f2bf(v.y); o.z = f2bf(v.z); o.w = f2bf(v.w);
    ((ushort4v*)xb)[i] = o;
  } else {
    int idx = bid - 4096;
    const int z = idx >> 10;
    idx &= 1023;
    const int bx = idx & 31, by = idx >> 5;
    const float* W = (z == 0) ? W0 : (z == 1) ? W1 : (z == 2) ? W2 : W3;
    u16* dst = (z < 3) ? (dqkv + (size_t)z * ND * ND) : dout;
    const int n0 = bx * 32, k0 = by * 32;
    const int tx = threadIdx.x & 31, ty = threadIdx.x >> 5;   // 32x8
#pragma unroll
    for (int i = 0; i < 4; ++i)
      tile[ty + i * 8][tx] = W[(size_t)(k0 + ty + i * 8) * ND + n0 + tx];
    __syncthreads();
#pragma unroll
    for (int i = 0; i < 4; ++i)
      dst[(size_t)(n0 + ty + i * 8) * ND + k0 + tx] = f2bf(tile[tx][ty + i * 8]);
  }
}

// ---------------- shared GEMM body, BK=64, XOR-swizzled + double-buffered LDS ----------------
// MODE 0 (QK): operand-SWAPPED MFMA -> acc = (x@W)^T fragments: lane owns 4
//   consecutive d at fixed s -> RoPE+QSCALE fused, 8B stores.
// MODE 1 (V):  normal orientation, direct VT [b][h][d][s] 8B packed stores.
// MODE 2 (out): fp32 rows.
template<int MI, int MODE>
__device__ __forceinline__ void gemm_body(
    u16* smem0, int bx, int by,
    const u16* __restrict__ A, const u16* __restrict__ BT,
    u16* __restrict__ qo, u16* __restrict__ ko, u16* __restrict__ vo,
    float* __restrict__ fo,
    const float* __restrict__ cosT, const float* __restrict__ sinT) {
  constexpr int BUFSZ = MI * 2048 + 8192;
  const int tid = threadIdx.x;
  const int w = tid >> 6, lane = tid & 63;
  const int lr = lane & 15, lg = lane >> 4;
  const int bm = by * (MI * 32), bn = bx << 7;
  const int wr = (w >> 1) * (MI * 16), wc = (w & 1) << 6;
  f32x4 acc[MI][4] = {};

  const int arow = tid >> 3;
  const int aslot = (tid & 7) ^ (arow & 7);
  const u16* ags = A + (size_t)(bm + arow) * ND + (aslot << 3);
  const u16* bgs = BT + (size_t)(bn + arow) * ND + (aslot << 3);

  int af_off[MI][2], bf_off[4][2];
#pragma unroll
  for (int mi = 0; mi < MI; ++mi)
#pragma unroll
    for (int kk = 0; kk < 2; ++kk)
      af_off[mi][kk] = (wr + mi * 16 + lr) * 64 + ((((kk << 2) + lg) ^ (lr & 7)) << 3);
#pragma unroll
  for (int ni = 0; ni < 4; ++ni)
#pragma unroll
    for (int kk = 0; kk < 2; ++kk)
      bf_off[ni][kk] = (wc + ni * 16 + lr) * 64 + ((((kk << 2) + lg) ^ (lr & 7)) << 3);

  auto stage = [&](int buf, int kt) {
    u16* dst = smem0 + buf * BUFSZ;
#pragma unroll
    for (int it = 0; it < MI; ++it)
      gld_lds16(ags + it * (32 * ND) + kt, dst + it * 2048 + w * 512);
#pragma unroll
    for (int it = 0; it < 4; ++it)
      gld_lds16(bgs + it * (32 * ND) + kt, dst + MI * 2048 + it * 2048 + w * 512);
  };

  stage(0, 0);
  __syncthreads();
  int cur = 0;
  for (int kt = 0; kt < ND; kt += 64) {
    if (kt + 64 < ND) stage(cur ^ 1, kt + 64);
    const u16* As = smem0 + cur * BUFSZ;
    const u16* Bs = As + MI * 2048;
#pragma unroll
    for (int kk = 0; kk < 2; ++kk) {
      short8 af[MI], bfr[4];
#pragma unroll
      for (int mi = 0; mi < MI; ++mi)
        af[mi] = *(const short8*)(As + af_off[mi][kk]);
#pragma unroll
      for (int ni = 0; ni < 4; ++ni)
        bfr[ni] = *(const short8*)(Bs + bf_off[ni][kk]);
#pragma unroll
      for (int mi = 0; mi < MI; ++mi)
#pragma unroll
        for (int ni = 0; ni < 4; ++ni) {
          if (MODE == 0)   // swapped operands: acc = (x@W)^T fragment
            acc[mi][ni] = __builtin_amdgcn_mfma_f32_16x16x32_bf16(bfr[ni], af[mi], acc[mi][ni], 0, 0, 0);
          else
            acc[mi][ni] = __builtin_amdgcn_mfma_f32_16x16x32_bf16(af[mi], bfr[ni], acc[mi][ni], 0, 0, 0);
        }
    }
    __syncthreads();
    cur ^= 1;
  }

  if (MODE == 0) {
    // acc[mi][ni][j]: row = n = bn+wc+ni*16+(lg<<2)+j (d-dim), col = s = bm+wr+mi*16+lr
#pragma unroll
    for (int mi = 0; mi < MI; ++mi) {
      const int m = bm + wr + mi * 16 + lr;
      const int b = m >> 11, s = m & 2047;
      const float* cbase = cosT + s * NHALF;
      const float* sbase = sinT + s * NHALF;
#pragma unroll
      for (int ni = 0; ni < 4; ++ni) {
        const int n = bn + wc + ni * 16 + (lg << 2);
        const int which = n >> 10, hh = (n >> 6) & 15, d0 = n & 63;
        u16* dst = which == 0 ? qo : ko;
        const float sc = which == 0 ? QSCALE : 1.0f;
        const float2 cp = *(const float2*)(cbase + (d0 >> 1));
        const float2 sp = *(const float2*)(sbase + (d0 >> 1));
        const float v0 = acc[mi][ni][0], v1 = acc[mi][ni][1];
        const float v2 = acc[mi][ni][2], v3 = acc[mi][ni][3];
        uint2v pk;
        pk.x = cvt_pk_bf16((v0 * cp.x - v1 * sp.x) * sc, (v0 * sp.x + v1 * cp.x) * sc);
        pk.y = cvt_pk_bf16((v2 * cp.y - v3 * sp.y) * sc, (v2 * sp.y + v3 * cp.y) * sc);
        *(uint2v*)(dst + (((size_t)(b * NH + hh) * NS + s) << 6) + d0) = pk;
      }
    }
  } else if (MODE == 1) {
    // normal orientation: lane holds 4 consecutive s at fixed d -> VT[b][h][d][s]
#pragma unroll
    for (int mi = 0; mi < MI; ++mi) {
#pragma unroll
      for (int ni = 0; ni < 4; ++ni) {
        const int n = bn + wc + ni * 16 + lr;         // d-index in [0,1024)
        const int hh = n >> 6, d = n & 63;
        const int m0 = bm + wr + mi * 16 + (lg << 2);
        const int b = m0 >> 11, s0 = m0 & 2047;
        uint2v pk;
        pk.x = cvt_pk_bf16(acc[mi][ni][0], acc[mi][ni][1]);
        pk.y = cvt_pk_bf16(acc[mi][ni][2], acc[mi][ni][3]);
        *(uint2v*)(vo + ((size_t)(b * NH + hh) * HDIM + d) * NS + s0) = pk;
      }
    }
  } else {
#pragma unroll
    for (int mi = 0; mi < MI; ++mi)
#pragma unroll
      for (int ni = 0; ni < 4; ++ni)
#pragma unroll
        for (int j = 0; j < 4; ++j) {
          const int m = bm + wr + mi * 16 + (lg << 2) + j;
          const int n = bn + wc + ni * 16 + lr;
          fo[(size_t)m * ND + n] = acc[mi][ni][j];
        }
  }
}

// Merged QKV projection: blocks 0..511 = QK (MI=4, fused RoPE), 512..1023 = V (MI=2 -> VT)
__global__ __launch_bounds__(256) void gemm_qkv(
    const u16* __restrict__ xb, const u16* __restrict__ WTqkv, const u16* __restrict__ WTv,
    u16* __restrict__ Qb, u16* __restrict__ Kb, u16* __restrict__ VT,
    const float* __restrict__ fc, const float* __restrict__ fs) {
  __shared__ u16 smem[2 * 16384];   // 64 KB: QK path 2x16384; V path uses 2x12288
  const int bid = blockIdx.x;
  if (bid < 512) {
    gemm_body<4, 0>(smem, bid & 15, bid >> 4, xb, WTqkv, Qb, Kb, nullptr, nullptr, fc, fs);
  } else {
    const int idx = bid - 512;
    gemm_body<2, 1>(smem, idx & 7, idx >> 3, xb, WTv, nullptr, nullptr, VT, nullptr, nullptr, nullptr);
  }
}

__global__ __launch_bounds__(256) void gemm_out_k(
    const u16* __restrict__ Ob, const u16* __restrict__ WTo, float* __restrict__ out) {
  __shared__ u16 smem[2 * 12288];
  gemm_body<2, 2>(smem, blockIdx.x, blockIdx.y, Ob, WTo, nullptr, nullptr, nullptr, out, nullptr, nullptr);
}

// ---------------- flash attention (causal), paired q-tiles, KVB=128 ----------------
// grid 512 (R8-proven geometry: 4 waves x 16 q-rows, 2 blocks/CU); block does
// q-tiles (31-pair) then (pair). KVB=128 halves kv-steps: 17 uniform barriers
// per block instead of 33. V/P LDS rows are 256B (16 slots) -> 16-way XOR
// swizzle; K rows stay 128B with the proven 8-way swizzle.
__global__ __launch_bounds__(256) void attn_k(
    const u16* __restrict__ Qb, const u16* __restrict__ Kb,
    const u16* __restrict__ VT, u16* __restrict__ Ob) {
  __shared__ u16 K2[2][8192];   // [kv=128][d=64], rows 128B, slot^=(row&7)
  __shared__ u16 V2[2][8192];   // [d=64][kv=128], rows 256B, slot^=(d&15)
  __shared__ u16 Pl[4][2048];   // per wave [q=16][kv=128], rows 256B, slot^=(lr&15)
  const int tid = threadIdx.x, w = tid >> 6, lane = tid & 63;
  const int lr = lane & 15, lg = lane >> 4;
  const int bid = blockIdx.x;
  const int xcd = bid & 7, i = bid >> 3;          // i in 0..63
  const int bh = xcd * 4 + (i & 3);
  const int pair = i >> 2;                        // 0..15
  const int b = bh >> 4, h = bh & 15;
  const u16* Qp = Qb + (size_t)bh * NS * HDIM;
  const u16* Kp = Kb + (size_t)bh * NS * HDIM;
  const u16* Vp = VT + (size_t)bh * NS * HDIM;    // [d][s]

  // hoisted swizzled LDS offsets (u16 units)
  int kf_off[8][2], vb_off[4][4], pw_off[8], pa_off[4];
#pragma unroll
  for (int u = 0; u < 8; ++u) {
    const int kvr = (u << 4) + lr;
#pragma unroll
    for (int c = 0; c < 2; ++c)
      kf_off[u][c] = kvr * 64 + ((((c << 6) + (lg << 4)) ^ ((kvr & 7) << 4)) >> 1);
  }
#pragma unroll
  for (int dn = 0; dn < 4; ++dn) {
    const int d = (dn << 4) + lr;
#pragma unroll
    for (int ks = 0; ks < 4; ++ks)
      vb_off[dn][ks] = d * 128 + ((((ks << 6) + (lg << 4)) ^ ((d & 15) << 4)) >> 1);
  }
#pragma unroll
  for (int u = 0; u < 8; ++u)
    pw_off[u] = lr * 128 + ((((u << 5) + (lg << 3)) ^ ((lr & 15) << 4)) >> 1);
#pragma unroll
  for (int ks = 0; ks < 4; ++ks)
    pa_off[ks] = lr * 128 + ((((ks << 6) + (lg << 4)) ^ ((lr & 15) << 4)) >> 1);
  u16* Pw = &Pl[w][0];

  // staging bases. K: 4 issues x (32 rows x 128B); thread row rr=tid>>3.
  // V: 4 issues x (16 rows x 256B); thread row vr=tid>>4, 16 slots.
  const int rr = tid >> 3, slot = tid & 7;
  const int ksoff = ((slot ^ (rr & 7)) << 3);
  const u16* kg = Kp + (size_t)rr * HDIM + ksoff;
  const int vr = tid >> 4, vslot = tid & 15;
  const int vsoff = ((vslot ^ vr) << 3);
  const u16* vg = Vp + (size_t)vr * NS + vsoff;

#define STAGE(BUFI, KV0)                                                            \
  {                                                                                 \
    _Pragma("unroll")                                                               \
    for (int c = 0; c < 4; ++c) {                                                   \
      gld_lds16(kg + (size_t)((KV0) + c * 32) * HDIM, &K2[BUFI][c * 2048 + w * 512]); \
      gld_lds16(vg + (size_t)(c * 16) * NS + (KV0),   &V2[BUFI][c * 2048 + w * 512]); \
    }                                                                               \
  }

#define STEP(BUF, KVT)                                                            \
  {                                                                               \
    const int kv0 = (KVT) << 7;                                                   \
    if ((KVT) + 1 < nst) STAGE(BUF ^ 1, kv0 + 128);                               \
    const u16* Kl = K2[BUF];                                                      \
    const u16* Vl = V2[BUF];                                                      \
    f32x4 st[8] = {};                                                             \
    __builtin_amdgcn_s_setprio(1);                                                \
    _Pragma("unroll") for (int u = 0; u < 8; ++u)                                 \
      _Pragma("unroll") for (int c = 0; c < 2; ++c)                               \
        st[u] = __builtin_amdgcn_mfma_f32_16x16x32_bf16(                          \
            *(const short8*)(Kl + kf_off[u][c]), qf[c], st[u], 0, 0, 0);          \
    __builtin_amdgcn_s_setprio(0);                                                \
    if (kv0 + 127 > qw) {                                                         \
      _Pragma("unroll") for (int u = 0; u < 8; ++u)                               \
        _Pragma("unroll") for (int j = 0; j < 4; ++j) {                           \
          const int kvg = kv0 + (u << 4) + (lg << 2) + j;                         \
          if (kvg > q_col) st[u][j] = NEGBIG;                                     \
        }                                                                         \
    }                                                                             \
    _Pragma("unroll") for (int u = 0; u < 8; ++u) {                               \
      const float e0 = __builtin_amdgcn_exp2f(st[u][0]);                          \
      const float e1 = __builtin_amdgcn_exp2f(st[u][1]);                          \
      const float e2 = __builtin_amdgcn_exp2f(st[u][2]);                          \
      const float e3 = __builtin_amdgcn_exp2f(st[u][3]);                          \
      lacc += (e0 + e1) + (e2 + e3);                                              \
      uint2v pk;                                                                  \
      pk.x = cvt_pk_bf16(e0, e1);                                                 \
      pk.y = cvt_pk_bf16(e2, e3);                                                 \
      *(uint2v*)(Pw + pw_off[u]) = pk;                                            \
    }                                                                             \
    {                                                                             \
      short8 pa[4];                                                               \
      _Pragma("unroll") for (int ks = 0; ks < 4; ++ks)                            \
        pa[ks] = *(const short8*)(Pw + pa_off[ks]);                               \
      __builtin_amdgcn_s_setprio(1);                                              \
      _Pragma("unroll") for (int dn = 0; dn < 4; ++dn)                            \
        _Pragma("unroll") for (int ks = 0; ks < 4; ++ks)                          \
          o[dn] = __builtin_amdgcn_mfma_f32_16x16x32_bf16(                        \
              pa[ks], *(const short8*)(Vl + vb_off[dn][ks]), o[dn], 0, 0, 0);     \
      __builtin_amdgcn_s_setprio(0);                                              \
    }                                                                             \
    __syncthreads();                                                              \
  }

  for (int seg = 0; seg < 2; ++seg) {
    const int tile = seg ? pair : 31 - pair;      // long tile first, short second
    const int q0 = tile << 6;
    const int qw = q0 + w * 16;
    const int q_col = qw + lr;
    const int nst = (tile + 2) >> 1;              // KVB=128 steps

    short8 qf[2];
#pragma unroll
    for (int c = 0; c < 2; ++c)
      qf[c] = *(const short8*)(Qp + (size_t)(qw + lr) * HDIM + c * 32 + lg * 8);

    f32x4 o[4] = {};
    float lacc = 0.f;

    STAGE(0, 0);
    __syncthreads();

    int kvt = 0;
    for (; kvt + 2 <= nst; kvt += 2) {
      STEP(0, kvt);
      STEP(1, kvt + 1);
    }
    if (kvt < nst) STEP(0, kvt);

    float rs = lacc;
    rs += __shfl_xor(rs, 16);
    rs += __shfl_xor(rs, 32);
    float li[4];
#pragma unroll
    for (int j = 0; j < 4; ++j) li[j] = 1.0f / __shfl(rs, (lg << 2) + j);
#pragma unroll
    for (int dn = 0; dn < 4; ++dn)
#pragma unroll
      for (int j = 0; j < 4; ++j) {
        const int m = b * NS + qw + (lg << 2) + j;
        const int col = h * 64 + dn * 16 + lr;
        Ob[(size_t)m * ND + col] = f2bf(o[dn][j] * li[j]);
      }
  }
}

extern "C" void kernel_launch(void* const* d_in, const int* in_sizes, int n_in,
                              void* d_out, int out_size, void* d_ws, size_t ws_size,
                              hipStream_t stream) {
  const float* x  = (const float*)d_in[0];
  const float* fc = (const float*)d_in[1];
  const float* fs = (const float*)d_in[2];
  const float* Wq = (const float*)d_in[3];
  const float* Wk = (const float*)d_in[4];
  const float* Wv = (const float*)d_in[5];
  const float* Wo = (const float*)d_in[6];
  float* out = (float*)d_out;
  char* ws = (char*)d_ws;

  // Workspace timeline (40 MB):
  //  0- 8MB: xb (dead after gemms) -> Ob
  //  8-14MB: WTqkv     14-16MB: WTo (written upfront, read at end)
  // 16-24MB: Qb        24-32MB: Kb
  // 32-40MB: VT (written DIRECTLY by V-gemm epilogue)
  u16* xb    = (u16*)(ws);
  u16* Ob    = (u16*)(ws);
  u16* WTqkv = (u16*)(ws + (size_t)(8u << 20));
  u16* WTo   = (u16*)(ws + (size_t)(14u << 20));
  u16* Qb    = (u16*)(ws + (size_t)(16u << 20));
  u16* Kb    = (u16*)(ws + (size_t)(24u << 20));
  u16* VT    = (u16*)(ws + (size_t)(32u << 20));
  u16* WTv   = WTqkv + (size_t)2 * ND * ND;

  prep<<<8192, 256, 0, stream>>>(x, xb, Wq, Wk, Wv, Wo, WTqkv, WTo);
  gemm_qkv<<<1024, 256, 0, stream>>>(xb, WTqkv, WTv, Qb, Kb, VT, fc, fs);
  attn_k<<<512, 256, 0, stream>>>(Qb, Kb, VT, Ob);
  gemm_out_k<<<dim3(8, 64), 256, 0, stream>>>(Ob, WTo, out);
}